// Round 1
// baseline (445.935 us; speedup 1.0000x reference)
//
#include <hip/hip_runtime.h>
#include <math.h>

#define NCLS 10
#define NB   16
#define NG   60
#define NA   33600          // 160*160 + 80*80 + 40*40
#define BA   (NB*NA)        // 537600

// ---- static device scratch (avoids any ws_size assumption) ----
__device__ double g_acc[4];                 // nfg, sum_iou, sum_obj, sum_cls
__device__ int    g_nmatch[BA];
__device__ int    g_gsum[BA];
__device__ int    g_fg[BA];
__device__ float  g_bx[BA], g_by[BA], g_bw[BA], g_bh[BA];
__device__ float  g_obj[BA], g_S[BA];
__device__ float  g_D[(size_t)NCLS*BA];     // class-major: D[c*BA + b*NA + a]

__device__ __forceinline__ void anchor_geom(int a, int& H, int& W, float& s, int& h, int& w, int& lvl) {
  if (a < 25600)      { lvl = 0; H = 160; W = 160; s = 8.f;  h = a / 160;            w = a - h*160; }
  else if (a < 32000) { lvl = 1; H = 80;  W = 80;  s = 16.f; int r = a - 25600; h = r / 80;  w = r - h*80; }
  else                { lvl = 2; H = 40;  W = 40;  s = 32.f; int r = a - 32000; h = r / 40;  w = r - h*40; }
}

__global__ __launch_bounds__(256) void init_kernel() {
  int i = blockIdx.x * 256 + threadIdx.x;
  if (i < 4) g_acc[i] = 0.0;
  if (i < BA) { g_nmatch[i] = 0; g_gsum[i] = 0; }
}

// ---- Kernel A: decode + per-anchor cls-cost precompute + fg flag ----
__global__ __launch_bounds__(256) void decode_kernel(const float* __restrict__ p0,
                                                     const float* __restrict__ p1,
                                                     const float* __restrict__ p2,
                                                     const float* __restrict__ lb) {
  __shared__ float lab[NG*5];
  __shared__ int   lval[NG];
  int b = blockIdx.y, tid = threadIdx.x;
  for (int i = tid; i < NG*5; i += 256) lab[i] = lb[(size_t)b*NG*5 + i];
  __syncthreads();
  if (tid < NG) {
    float s = lab[tid*5] + lab[tid*5+1] + lab[tid*5+2] + lab[tid*5+3] + lab[tid*5+4];
    lval[tid] = (s > 0.f) ? 1 : 0;
  }
  __syncthreads();
  int a = blockIdx.x * 256 + tid;
  if (a >= NA) return;

  int H, W, h, w, lvl; float st;
  anchor_geom(a, H, W, st, h, w, lvl);
  const float* pp = (lvl == 0) ? p0 : ((lvl == 1) ? p1 : p2);
  size_t cs = (size_t)H * W;
  size_t base = (size_t)b * 15 * cs + (size_t)h * W + w;

  float tx = pp[base], ty = pp[base+cs], tw = pp[base+2*cs], th = pp[base+3*cs], to = pp[base+4*cs];
  int idx = b * NA + a;
  g_bx[idx] = (tx + (float)w) * st;
  g_by[idx] = (ty + (float)h) * st;
  g_bw[idx] = expf(tw) * st;
  g_bh[idx] = expf(th) * st;
  g_obj[idx] = to;

  float so = 1.f / (1.f + expf(-to));
  float S = 0.f;
  for (int c = 0; c < NCLS; c++) {
    float xl = pp[base + (size_t)(5 + c) * cs];
    float sc = 1.f / (1.f + expf(-xl));
    float p  = sqrtf(sc * so);
    float L  = logf(p + 1e-12f);
    float M  = logf(1.f - p + 1e-12f);
    S += M;
    g_D[(size_t)c*BA + idx] = L - M;
  }
  g_S[idx] = S;

  float xc = ((float)w + 0.5f) * st;
  float yc = ((float)h + 0.5f) * st;
  float rad = 2.5f * st;
  int fg = 0;
  for (int g = 0; g < NG; g++) {
    if (!lval[g]) continue;
    float gx = lab[g*5+1], gy = lab[g*5+2], gw = lab[g*5+3], gh = lab[g*5+4];
    float l  = xc - (gx - gw*0.5f);
    float r  = (gx + gw*0.5f) - xc;
    float t  = yc - (gy - gh*0.5f);
    float bo = (gy + gh*0.5f) - yc;
    float m1 = fminf(fminf(l, r), fminf(t, bo));
    float cl = xc - gx + rad, cr = gx + rad - xc, ct = yc - gy + rad, cb = gy + rad - yc;
    float m2 = fminf(fminf(cl, cr), fminf(ct, cb));
    if (m1 > 0.f || m2 > 0.f) { fg = 1; break; }
  }
  g_fg[idx] = fg;
}

// ---- Kernel B: per-(b,g) top-10 by cost (with index tie-break) + dyn_k + match scatter ----
__global__ __launch_bounds__(256) void topk_kernel(const float* __restrict__ lb) {
  __shared__ float bufV[2][2560];
  __shared__ int   bufI[2][2560];
  __shared__ int   finIdx[10];
  __shared__ float sgt[5];
  __shared__ int   sgood;
  int g = blockIdx.x, b = blockIdx.y, tid = threadIdx.x;

  if (tid == 0) {
    float su = 0.f;
    for (int i = 0; i < 5; i++) { float v = lb[((size_t)b*NG + g)*5 + i]; sgt[i] = v; su += v; }
    sgood = (su > 0.f) ? 1 : 0;
  }
  __syncthreads();
  if (!sgood) return;

  int   gc = (int)sgt[0];
  float gx = sgt[1], gy = sgt[2], gw = sgt[3], gh = sgt[4];
  float a1x = gx - gw*0.5f, a1y = gy - gh*0.5f, a2x = gx + gw*0.5f, a2y = gy + gh*0.5f;
  float garea = gw * gh;
  const float* Dc = &g_D[(size_t)gc*BA];
  int bbase = b * NA;

  float cv[10]; int ci[10]; float iv[10];
  #pragma unroll
  for (int k = 0; k < 10; k++) { cv[k] = INFINITY; ci[k] = 0x7FFFFFFF; iv[k] = 0.f; }

  for (int a = tid; a < NA; a += 256) {
    int idx = bbase + a;
    float px = g_bx[idx], py = g_by[idx], pw = g_bw[idx], ph = g_bh[idx];
    float b1x = px - pw*0.5f, b1y = py - ph*0.5f, b2x = px + pw*0.5f, b2y = py + ph*0.5f;
    float wx = fminf(a2x, b2x) - fmaxf(a1x, b1x); wx = wx > 0.f ? wx : 0.f;
    float wy = fminf(a2y, b2y) - fmaxf(a1y, b1y); wy = wy > 0.f ? wy : 0.f;
    float inter = wx * wy;
    float iou = inter / (garea + pw*ph - inter + 1e-8f);
    int fg = g_fg[idx];

    int H, W, h, w, lvl; float st;
    anchor_geom(a, H, W, st, h, w, lvl);
    float xc = ((float)w + 0.5f) * st;
    float yc = ((float)h + 0.5f) * st;
    float l  = xc - a1x, r = a2x - xc, t = yc - a1y, bo = a2y - yc;
    bool inb = fminf(fminf(l, r), fminf(t, bo)) > 0.f;
    float rad = 2.5f * st;
    float cl = xc - gx + rad, cr = gx + rad - xc, ct = yc - gy + rad, cb = gy + rad - yc;
    bool inc = fminf(fminf(cl, cr), fminf(ct, cb)) > 0.f;

    float clsc = -(Dc[idx] + g_S[idx]);
    float cost = clsc + 3.0f * (-logf(iou + 1e-8f));
    if (!(inb && inc)) cost += 100000.0f;
    if (!fg)           cost += 1000000.0f;

    // insert into ascending (cost, idx) top-10 — static-indexed bubble, stays in registers
    if (cost < cv[9] || (cost == cv[9] && a < ci[9])) {
      cv[9] = cost; ci[9] = a;
      #pragma unroll
      for (int k = 9; k > 0; k--) {
        bool sw = (cv[k] < cv[k-1]) || (cv[k] == cv[k-1] && ci[k] < ci[k-1]);
        if (sw) {
          float tv = cv[k]; cv[k] = cv[k-1]; cv[k-1] = tv;
          int   ti = ci[k]; ci[k] = ci[k-1]; ci[k-1] = ti;
        }
      }
    }
    float ioufg = fg ? iou : 0.f;
    if (ioufg > iv[9]) {
      iv[9] = ioufg;
      #pragma unroll
      for (int k = 9; k > 0; k--) {
        if (iv[k] > iv[k-1]) { float tv = iv[k]; iv[k] = iv[k-1]; iv[k-1] = tv; }
      }
    }
  }

  // ---- phase 1: tree-merge cost lists (ascending lex) ----
  #pragma unroll
  for (int k = 0; k < 10; k++) { bufV[0][tid*10+k] = cv[k]; bufI[0][tid*10+k] = ci[k]; }
  __syncthreads();
  int src = 0;
  for (int sA = 128; sA >= 1; sA >>= 1) {
    int dst = src ^ 1;
    if (tid < sA) {
      int i = 0, j = 0;
      int pa = tid*10, pb = (tid + sA)*10;
      #pragma unroll
      for (int k = 0; k < 10; k++) {
        float va = bufV[src][pa+i]; int ia = bufI[src][pa+i];
        float vb = bufV[src][pb+j]; int ib = bufI[src][pb+j];
        bool ta = (va < vb) || (va == vb && ia < ib);
        bufV[dst][tid*10+k] = ta ? va : vb;
        bufI[dst][tid*10+k] = ta ? ia : ib;
        if (ta) i++; else j++;
      }
    }
    __syncthreads();
    src = dst;
  }
  if (tid == 0) {
    #pragma unroll
    for (int k = 0; k < 10; k++) finIdx[k] = bufI[src][k];
  }
  __syncthreads();

  // ---- phase 2: tree-merge iou lists (descending) ----
  #pragma unroll
  for (int k = 0; k < 10; k++) bufV[0][tid*10+k] = iv[k];
  __syncthreads();
  src = 0;
  for (int sA = 128; sA >= 1; sA >>= 1) {
    int dst = src ^ 1;
    if (tid < sA) {
      int i = 0, j = 0;
      int pa = tid*10, pb = (tid + sA)*10;
      #pragma unroll
      for (int k = 0; k < 10; k++) {
        float va = bufV[src][pa+i];
        float vb = bufV[src][pb+j];
        bool ta = (va > vb);
        bufV[dst][tid*10+k] = ta ? va : vb;
        if (ta) i++; else j++;
      }
    }
    __syncthreads();
    src = dst;
  }

  if (tid == 0) {
    float ss = 0.f;
    #pragma unroll
    for (int k = 0; k < 10; k++) ss += bufV[src][k];
    int dynk = (int)ss;           // truncation toward zero, matches astype(int32)
    if (dynk < 1)  dynk = 1;
    if (dynk > 10) dynk = 10;
    for (int k = 0; k < dynk; k++) {
      int a = finIdx[k];
      atomicAdd(&g_nmatch[b*NA + a], 1);
      atomicAdd(&g_gsum[b*NA + a], g);
    }
  }
}

__device__ __forceinline__ double block_reduce(double v, double* red, int tid) {
  red[tid] = v; __syncthreads();
  for (int s = 128; s > 0; s >>= 1) { if (tid < s) red[tid] += red[tid+s]; __syncthreads(); }
  double r = red[0]; __syncthreads();
  return r;
}

// ---- Kernel C: dedup (argmin over g), per-anchor losses, block reduce ----
__global__ __launch_bounds__(256) void loss_kernel(const float* __restrict__ p0,
                                                   const float* __restrict__ p1,
                                                   const float* __restrict__ p2,
                                                   const float* __restrict__ lb) {
  __shared__ float  lab[NG*5];
  __shared__ int    lval[NG];
  __shared__ double red[256];
  int b = blockIdx.y, tid = threadIdx.x;
  for (int i = tid; i < NG*5; i += 256) lab[i] = lb[(size_t)b*NG*5 + i];
  __syncthreads();
  if (tid < NG) {
    float s = lab[tid*5] + lab[tid*5+1] + lab[tid*5+2] + lab[tid*5+3] + lab[tid*5+4];
    lval[tid] = (s > 0.f) ? 1 : 0;
  }
  __syncthreads();

  int a = blockIdx.x * 256 + tid;
  double t_nfg = 0.0, t_iou = 0.0, t_obj = 0.0, t_cls = 0.0;

  if (a < NA) {
    int idx = b * NA + a;
    float x  = g_obj[idx];
    int   nm = g_nmatch[idx];
    float t  = (nm > 0) ? 1.f : 0.f;
    float bce = fmaxf(x, 0.f) - x * t + log1pf(expf(-fabsf(x)));
    float pr  = 1.f / (1.f + expf(-x));
    float pt  = (nm > 0) ? pr : (1.f - pr);
    float wf  = (nm > 0) ? 0.25f : 0.75f;
    float om  = 1.f - pt;
    t_obj = (double)(bce * wf * om * om);

    if (nm > 0) {
      t_nfg = 1.0;
      float px = g_bx[idx], py = g_by[idx], pw = g_bw[idx], ph = g_bh[idx];
      float b1x = px - pw*0.5f, b1y = py - ph*0.5f, b2x = px + pw*0.5f, b2y = py + ph*0.5f;
      int mg;
      if (nm == 1) {
        mg = g_gsum[idx];
      } else {
        int H, W, h, w, lvl; float st;
        anchor_geom(a, H, W, st, h, w, lvl);
        float xc = ((float)w + 0.5f) * st, yc = ((float)h + 0.5f) * st, rad = 2.5f * st;
        float S = g_S[idx];
        int fg = g_fg[idx];
        float best = INFINITY; int bg = 0;
        for (int g = 0; g < NG; g++) {
          float gx = lab[g*5+1], gy = lab[g*5+2], gw = lab[g*5+3], gh = lab[g*5+4];
          int gcl = (int)lab[g*5];
          int v = lval[g];
          float a1x = gx - gw*0.5f, a1y = gy - gh*0.5f, a2x = gx + gw*0.5f, a2y = gy + gh*0.5f;
          float wx = fminf(a2x, b2x) - fmaxf(a1x, b1x); wx = wx > 0.f ? wx : 0.f;
          float wy = fminf(a2y, b2y) - fmaxf(a1y, b1y); wy = wy > 0.f ? wy : 0.f;
          float inter = wx * wy;
          float iou = inter / (gw*gh + pw*ph - inter + 1e-8f);
          float l = xc - a1x, r = a2x - xc, tt = yc - a1y, bo = a2y - yc;
          bool inb = (fminf(fminf(l, r), fminf(tt, bo)) > 0.f) && v;
          float cl = xc - gx + rad, cr = gx + rad - xc, ct = yc - gy + rad, cb = gy + rad - yc;
          bool inc = (fminf(fminf(cl, cr), fminf(ct, cb)) > 0.f) && v;
          float clsc = -(g_D[(size_t)gcl*BA + idx] + S);
          float cost = clsc + 3.0f * (-logf(iou + 1e-8f));
          if (!(inb && inc)) cost += 100000.0f;
          if (!fg || !v)     cost += 1000000.0f;
          if (cost < best) { best = cost; bg = g; }   // strict < : first-index tie-break
        }
        mg = bg;
      }

      float gx = lab[mg*5+1], gy = lab[mg*5+2], gw = lab[mg*5+3], gh = lab[mg*5+4];
      int mcls = (int)lab[mg*5];
      float a1x = gx - gw*0.5f, a1y = gy - gh*0.5f, a2x = gx + gw*0.5f, a2y = gy + gh*0.5f;
      float wx = fminf(a2x, b2x) - fmaxf(a1x, b1x); wx = wx > 0.f ? wx : 0.f;
      float wy = fminf(a2y, b2y) - fmaxf(a1y, b1y); wy = wy > 0.f ? wy : 0.f;
      float inter = wx * wy;
      float miou = inter / (gw*gh + pw*ph - inter + 1e-8f);  // == forward-loss IoU bit-exact

      t_iou = (double)(1.f - miou * miou);

      int H, W, h, w, lvl; float st;
      anchor_geom(a, H, W, st, h, w, lvl);
      const float* pp = (lvl == 0) ? p0 : ((lvl == 1) ? p1 : p2);
      size_t cs = (size_t)H * W;
      size_t base = (size_t)b * 15 * cs + (size_t)h * W + w;
      float sc = 0.f;
      for (int c = 0; c < NCLS; c++) {
        float xl = pp[base + (size_t)(5 + c) * cs];
        float ctg = (c == mcls) ? miou : 0.f;
        sc += fmaxf(xl, 0.f) - xl * ctg + log1pf(expf(-fabsf(xl)));
      }
      t_cls = (double)sc;
    }
  }

  double r0 = block_reduce(t_nfg, red, tid);
  double r1 = block_reduce(t_iou, red, tid);
  double r2 = block_reduce(t_obj, red, tid);
  double r3 = block_reduce(t_cls, red, tid);
  if (tid == 0) {
    atomicAdd(&g_acc[0], r0);
    atomicAdd(&g_acc[1], r1);
    atomicAdd(&g_acc[2], r2);
    atomicAdd(&g_acc[3], r3);
  }
}

__global__ void final_kernel(float* __restrict__ out) {
  if (threadIdx.x == 0 && blockIdx.x == 0) {
    double nfg = g_acc[0];
    double num = (nfg < 1.0) ? 1.0 : nfg;
    float li = (float)(g_acc[1] / num);
    float lo = (float)(g_acc[2] / num);
    float lc = (float)(g_acc[3] / num);
    out[0] = 5.0f * li + lo;   // REG_W * loss_iou + loss_obj
    out[1] = li;
    out[2] = lo;
    out[3] = lc;
  }
}

extern "C" void kernel_launch(void* const* d_in, const int* in_sizes, int n_in,
                              void* d_out, int out_size, void* d_ws, size_t ws_size,
                              hipStream_t stream) {
  const float* p0 = (const float*)d_in[0];
  const float* p1 = (const float*)d_in[1];
  const float* p2 = (const float*)d_in[2];
  const float* lb = (const float*)d_in[3];
  float* out = (float*)d_out;

  hipLaunchKernelGGL(init_kernel,   dim3((BA + 255) / 256), dim3(256), 0, stream);
  hipLaunchKernelGGL(decode_kernel, dim3((NA + 255) / 256, NB), dim3(256), 0, stream, p0, p1, p2, lb);
  hipLaunchKernelGGL(topk_kernel,   dim3(NG, NB), dim3(256), 0, stream, lb);
  hipLaunchKernelGGL(loss_kernel,   dim3((NA + 255) / 256, NB), dim3(256), 0, stream, p0, p1, p2, lb);
  hipLaunchKernelGGL(final_kernel,  dim3(1), dim3(64), 0, stream, out);
}

// Round 2
// 379.518 us; speedup vs baseline: 1.1750x; 1.1750x over previous
//
#include <hip/hip_runtime.h>
#include <math.h>

#define NCLS 10
#define NB   16
#define NG   60
#define NA   33600          // 160*160 + 80*80 + 40*40
#define BA   (NB*NA)        // 537600
#define NSPLIT 2
#define HALF (NA/NSPLIT)    // 16800

// ---- static device scratch ----
__device__ double g_acc[4];                 // nfg, sum_iou, sum_obj, sum_cls
__device__ int    g_nmatch[BA];
__device__ int    g_gsum[BA];
__device__ float4 g_box[BA];                // bx, by, bw, bh
__device__ float4 g_meta[BA];               // xc, yc, (fg ? rad : -rad), S
__device__ float  g_obj[BA];
__device__ float  g_D[(size_t)NCLS*BA];     // class-major: D[c*BA + b*NA + a]
// per-(b,g,split,wave) sorted top-10 lists
__device__ float  s_cost[(size_t)NB*NG*NSPLIT*4*10];
__device__ int    s_idx [(size_t)NB*NG*NSPLIT*4*10];
__device__ float  s_iou [(size_t)NB*NG*NSPLIT*4*10];

__device__ __forceinline__ void anchor_geom(int a, int& H, int& W, float& s, int& h, int& w, int& lvl) {
  if (a < 25600)      { lvl = 0; H = 160; W = 160; s = 8.f;  h = a / 160;            w = a - h*160; }
  else if (a < 32000) { lvl = 1; H = 80;  W = 80;  s = 16.f; int r = a - 25600; h = r / 80;  w = r - h*80; }
  else                { lvl = 2; H = 40;  W = 40;  s = 32.f; int r = a - 32000; h = r / 40;  w = r - h*40; }
}

// ---- Kernel A: init + decode + per-anchor cls-cost precompute + fg flag ----
__global__ __launch_bounds__(256) void decode_kernel(const float* __restrict__ p0,
                                                     const float* __restrict__ p1,
                                                     const float* __restrict__ p2,
                                                     const float* __restrict__ lb) {
  __shared__ float lab[NG*5];
  __shared__ int   lval[NG];
  int b = blockIdx.y, tid = threadIdx.x;
  if (b == 0 && blockIdx.x == 0 && tid < 4) g_acc[tid] = 0.0;
  for (int i = tid; i < NG*5; i += 256) lab[i] = lb[(size_t)b*NG*5 + i];
  __syncthreads();
  if (tid < NG) {
    float s = lab[tid*5] + lab[tid*5+1] + lab[tid*5+2] + lab[tid*5+3] + lab[tid*5+4];
    lval[tid] = (s > 0.f) ? 1 : 0;
  }
  __syncthreads();
  int a = blockIdx.x * 256 + tid;
  if (a >= NA) return;
  int idx = b * NA + a;
  g_nmatch[idx] = 0;
  g_gsum[idx]   = 0;

  int H, W, h, w, lvl; float st;
  anchor_geom(a, H, W, st, h, w, lvl);
  const float* pp = (lvl == 0) ? p0 : ((lvl == 1) ? p1 : p2);
  size_t cs = (size_t)H * W;
  size_t base = (size_t)b * 15 * cs + (size_t)h * W + w;

  float tx = pp[base], ty = pp[base+cs], tw = pp[base+2*cs], th = pp[base+3*cs], to = pp[base+4*cs];
  float bx = (tx + (float)w) * st;
  float by = (ty + (float)h) * st;
  float bw = expf(tw) * st;
  float bh = expf(th) * st;
  g_box[idx] = make_float4(bx, by, bw, bh);
  g_obj[idx] = to;

  float so = 1.f / (1.f + expf(-to));
  float S = 0.f;
  for (int c = 0; c < NCLS; c++) {
    float xl = pp[base + (size_t)(5 + c) * cs];
    float sc = 1.f / (1.f + expf(-xl));
    float p  = sqrtf(sc * so);
    float L  = logf(p + 1e-12f);
    float M  = logf(1.f - p + 1e-12f);
    S += M;
    g_D[(size_t)c*BA + idx] = L - M;
  }

  float xc = ((float)w + 0.5f) * st;
  float yc = ((float)h + 0.5f) * st;
  float rad = 2.5f * st;
  int fg = 0;
  for (int g = 0; g < NG; g++) {
    if (!lval[g]) continue;
    float gx = lab[g*5+1], gy = lab[g*5+2], gw = lab[g*5+3], gh = lab[g*5+4];
    float l  = xc - (gx - gw*0.5f);
    float r  = (gx + gw*0.5f) - xc;
    float t  = yc - (gy - gh*0.5f);
    float bo = (gy + gh*0.5f) - yc;
    float m1 = fminf(fminf(l, r), fminf(t, bo));
    float cl = xc - gx + rad, cr = gx + rad - xc, ct = yc - gy + rad, cb = gy + rad - yc;
    float m2 = fminf(fminf(cl, cr), fminf(ct, cb));
    if (m1 > 0.f || m2 > 0.f) { fg = 1; break; }
  }
  g_meta[idx] = make_float4(xc, yc, fg ? rad : -rad, S);
}

// ---- Kernel B1: per-(b,g,split) register top-10 + wave butterfly merge ----
__global__ __launch_bounds__(256) void topk1_kernel(const float* __restrict__ lb) {
  int g = blockIdx.x, b = blockIdx.y, s = blockIdx.z;
  int tid = threadIdx.x;
  const float* L = &lb[((size_t)b*NG + g)*5];
  float l0 = L[0], l1 = L[1], l2 = L[2], l3 = L[3], l4 = L[4];
  if (!(l0 + l1 + l2 + l3 + l4 > 0.f)) return;

  int   gc = (int)l0;
  float gx = l1, gy = l2, gw = l3, gh = l4;
  float a1x = gx - gw*0.5f, a1y = gy - gh*0.5f, a2x = gx + gw*0.5f, a2y = gy + gh*0.5f;
  float garea = gw * gh;
  const float* Dc = &g_D[(size_t)gc*BA];
  int bbase = b * NA;

  float cv[10]; int ci[10]; float iv[10];
  #pragma unroll
  for (int k = 0; k < 10; k++) { cv[k] = INFINITY; ci[k] = 0x7FFFFFFF; iv[k] = 0.f; }

  auto ins_cost = [&](float c, int i) {
    if (c < cv[9] || (c == cv[9] && i < ci[9])) {
      cv[9] = c; ci[9] = i;
      #pragma unroll
      for (int k = 9; k > 0; k--) {
        bool sw = (cv[k] < cv[k-1]) || (cv[k] == cv[k-1] && ci[k] < ci[k-1]);
        if (sw) {
          float tv = cv[k]; cv[k] = cv[k-1]; cv[k-1] = tv;
          int   ti = ci[k]; ci[k] = ci[k-1]; ci[k-1] = ti;
        }
      }
    }
  };
  auto ins_iou = [&](float w) {
    if (w > iv[9]) {
      iv[9] = w;
      #pragma unroll
      for (int k = 9; k > 0; k--) {
        if (iv[k] > iv[k-1]) { float tv = iv[k]; iv[k] = iv[k-1]; iv[k-1] = tv; }
      }
    }
  };

  auto body = [&](int a) {
    int idx = bbase + a;
    float4 B = g_box[idx];
    float4 M = g_meta[idx];
    float Dv = Dc[idx];
    float b1x = B.x - B.z*0.5f, b1y = B.y - B.w*0.5f;
    float b2x = B.x + B.z*0.5f, b2y = B.y + B.w*0.5f;
    float wx = fminf(a2x, b2x) - fmaxf(a1x, b1x); wx = wx > 0.f ? wx : 0.f;
    float wy = fminf(a2y, b2y) - fmaxf(a1y, b1y); wy = wy > 0.f ? wy : 0.f;
    float inter = wx * wy;
    float iou = inter / (garea + B.z*B.w - inter + 1e-8f);
    bool  fg  = M.z > 0.f;
    float rad = fabsf(M.z);
    float xc = M.x, yc = M.y;
    bool inb = fminf(fminf(xc - a1x, a2x - xc), fminf(yc - a1y, a2y - yc)) > 0.f;
    bool inc = fminf(fminf(xc - gx + rad, gx + rad - xc), fminf(yc - gy + rad, gy + rad - yc)) > 0.f;
    float cost = -(Dv + M.w) + 3.0f * (-logf(iou + 1e-8f));
    if (!(inb && inc)) cost += 100000.0f;
    if (!fg)           cost += 1000000.0f;
    ins_cost(cost, a);
    ins_iou(fg ? iou : 0.f);
  };

  int a    = s * HALF + tid;
  int aend = s * HALF + HALF;
  for (; a + 256 < aend; a += 512) { body(a); body(a + 256); }
  if (a < aend) body(a);

  // wave butterfly merge: complementary lanes always hold disjoint anchor sets
  #pragma unroll
  for (int m = 1; m < 64; m <<= 1) {
    float pv[10]; int pi[10]; float pu[10];
    #pragma unroll
    for (int k = 0; k < 10; k++) {
      pv[k] = __shfl_xor(cv[k], m);
      pi[k] = __shfl_xor(ci[k], m);
      pu[k] = __shfl_xor(iv[k], m);
    }
    #pragma unroll
    for (int k = 0; k < 10; k++) { ins_cost(pv[k], pi[k]); ins_iou(pu[k]); }
  }

  if ((tid & 63) == 0) {
    int w = tid >> 6;
    size_t slot = (((((size_t)b*NG + g)*NSPLIT + s)*4) + w) * 10;
    #pragma unroll
    for (int k = 0; k < 10; k++) {
      s_cost[slot+k] = cv[k];
      s_idx [slot+k] = ci[k];
      s_iou [slot+k] = iv[k];
    }
  }
}

// ---- Kernel B2: merge 8 wave-lists per (b,g), dyn_k, scatter matches ----
__global__ __launch_bounds__(256) void topk2_kernel(const float* __restrict__ lb) {
  int t = blockIdx.x * 256 + threadIdx.x;
  if (t >= NB * NG) return;
  int b = t / NG, g = t - b * NG;
  const float* L = &lb[(size_t)t * 5];
  if (!(L[0] + L[1] + L[2] + L[3] + L[4] > 0.f)) return;

  size_t base = (size_t)t * (NSPLIT*4*10);
  float cv[10]; int ci[10]; float iv[10];
  #pragma unroll
  for (int k = 0; k < 10; k++) { cv[k] = s_cost[base+k]; ci[k] = s_idx[base+k]; iv[k] = s_iou[base+k]; }

  for (int l = 1; l < NSPLIT*4; l++) {
    size_t o = base + (size_t)l*10;
    #pragma unroll
    for (int k = 0; k < 10; k++) {
      float c = s_cost[o+k]; int i2 = s_idx[o+k]; float w = s_iou[o+k];
      if (c < cv[9] || (c == cv[9] && i2 < ci[9])) {
        cv[9] = c; ci[9] = i2;
        #pragma unroll
        for (int k2 = 9; k2 > 0; k2--) {
          bool sw = (cv[k2] < cv[k2-1]) || (cv[k2] == cv[k2-1] && ci[k2] < ci[k2-1]);
          if (sw) {
            float tv = cv[k2]; cv[k2] = cv[k2-1]; cv[k2-1] = tv;
            int   ti = ci[k2]; ci[k2] = ci[k2-1]; ci[k2-1] = ti;
          }
        }
      }
      if (w > iv[9]) {
        iv[9] = w;
        #pragma unroll
        for (int k2 = 9; k2 > 0; k2--) {
          if (iv[k2] > iv[k2-1]) { float tv = iv[k2]; iv[k2] = iv[k2-1]; iv[k2-1] = tv; }
        }
      }
    }
  }

  float ss = 0.f;
  #pragma unroll
  for (int k = 0; k < 10; k++) ss += iv[k];   // descending order, same sum order as ref
  int dynk = (int)ss;
  if (dynk < 1)  dynk = 1;
  if (dynk > 10) dynk = 10;
  for (int k = 0; k < dynk; k++) {
    int a = ci[k];
    atomicAdd(&g_nmatch[b*NA + a], 1);
    atomicAdd(&g_gsum[b*NA + a], g);
  }
}

// ---- Kernel C: dedup (argmin over g), per-anchor losses, fused block reduce ----
__global__ __launch_bounds__(256) void loss_kernel(const float* __restrict__ p0,
                                                   const float* __restrict__ p1,
                                                   const float* __restrict__ p2,
                                                   const float* __restrict__ lb) {
  __shared__ float  lab[NG*5];
  __shared__ int    lval[NG];
  __shared__ double red[256*4];
  int b = blockIdx.y, tid = threadIdx.x;
  for (int i = tid; i < NG*5; i += 256) lab[i] = lb[(size_t)b*NG*5 + i];
  __syncthreads();
  if (tid < NG) {
    float s = lab[tid*5] + lab[tid*5+1] + lab[tid*5+2] + lab[tid*5+3] + lab[tid*5+4];
    lval[tid] = (s > 0.f) ? 1 : 0;
  }
  __syncthreads();

  int a = blockIdx.x * 256 + tid;
  double t_nfg = 0.0, t_iou = 0.0, t_obj = 0.0, t_cls = 0.0;

  if (a < NA) {
    int idx = b * NA + a;
    float x  = g_obj[idx];
    int   nm = g_nmatch[idx];
    float t  = (nm > 0) ? 1.f : 0.f;
    float bce = fmaxf(x, 0.f) - x * t + log1pf(expf(-fabsf(x)));
    float pr  = 1.f / (1.f + expf(-x));
    float pt  = (nm > 0) ? pr : (1.f - pr);
    float wf  = (nm > 0) ? 0.25f : 0.75f;
    float om  = 1.f - pt;
    t_obj = (double)(bce * wf * om * om);

    if (nm > 0) {
      t_nfg = 1.0;
      float4 B = g_box[idx];
      float4 Mt = g_meta[idx];
      float px = B.x, py = B.y, pw = B.z, ph = B.w;
      float b1x = px - pw*0.5f, b1y = py - ph*0.5f, b2x = px + pw*0.5f, b2y = py + ph*0.5f;
      int mg;
      if (nm == 1) {
        mg = g_gsum[idx];
      } else {
        float xc = Mt.x, yc = Mt.y, rad = fabsf(Mt.z), S = Mt.w;
        int fg = (Mt.z > 0.f) ? 1 : 0;
        float best = INFINITY; int bg = 0;
        for (int g = 0; g < NG; g++) {
          float gx = lab[g*5+1], gy = lab[g*5+2], gw = lab[g*5+3], gh = lab[g*5+4];
          int gcl = (int)lab[g*5];
          int v = lval[g];
          float a1x = gx - gw*0.5f, a1y = gy - gh*0.5f, a2x = gx + gw*0.5f, a2y = gy + gh*0.5f;
          float wx = fminf(a2x, b2x) - fmaxf(a1x, b1x); wx = wx > 0.f ? wx : 0.f;
          float wy = fminf(a2y, b2y) - fmaxf(a1y, b1y); wy = wy > 0.f ? wy : 0.f;
          float inter = wx * wy;
          float iou = inter / (gw*gh + pw*ph - inter + 1e-8f);
          float l = xc - a1x, r = a2x - xc, tt = yc - a1y, bo = a2y - yc;
          bool inb = (fminf(fminf(l, r), fminf(tt, bo)) > 0.f) && v;
          float cl = xc - gx + rad, cr = gx + rad - xc, ct = yc - gy + rad, cb = gy + rad - yc;
          bool inc = (fminf(fminf(cl, cr), fminf(ct, cb)) > 0.f) && v;
          float clsc = -(g_D[(size_t)gcl*BA + idx] + S);
          float cost = clsc + 3.0f * (-logf(iou + 1e-8f));
          if (!(inb && inc)) cost += 100000.0f;
          if (!fg || !v)     cost += 1000000.0f;
          if (cost < best) { best = cost; bg = g; }   // strict < : first-index tie-break
        }
        mg = bg;
      }

      float gx = lab[mg*5+1], gy = lab[mg*5+2], gw = lab[mg*5+3], gh = lab[mg*5+4];
      int mcls = (int)lab[mg*5];
      float a1x = gx - gw*0.5f, a1y = gy - gh*0.5f, a2x = gx + gw*0.5f, a2y = gy + gh*0.5f;
      float wx = fminf(a2x, b2x) - fmaxf(a1x, b1x); wx = wx > 0.f ? wx : 0.f;
      float wy = fminf(a2y, b2y) - fmaxf(a1y, b1y); wy = wy > 0.f ? wy : 0.f;
      float inter = wx * wy;
      float miou = inter / (gw*gh + pw*ph - inter + 1e-8f);  // == forward-loss IoU bit-exact

      t_iou = (double)(1.f - miou * miou);

      int H, W, h, w, lvl; float st;
      anchor_geom(a, H, W, st, h, w, lvl);
      const float* pp = (lvl == 0) ? p0 : ((lvl == 1) ? p1 : p2);
      size_t cs = (size_t)H * W;
      size_t base = (size_t)b * 15 * cs + (size_t)h * W + w;
      float sc = 0.f;
      for (int c = 0; c < NCLS; c++) {
        float xl = pp[base + (size_t)(5 + c) * cs];
        float ctg = (c == mcls) ? miou : 0.f;
        sc += fmaxf(xl, 0.f) - xl * ctg + log1pf(expf(-fabsf(xl)));
      }
      t_cls = (double)sc;
    }
  }

  red[tid*4+0] = t_nfg; red[tid*4+1] = t_iou; red[tid*4+2] = t_obj; red[tid*4+3] = t_cls;
  __syncthreads();
  for (int s = 128; s > 0; s >>= 1) {
    if (tid < s) {
      red[tid*4+0] += red[(tid+s)*4+0];
      red[tid*4+1] += red[(tid+s)*4+1];
      red[tid*4+2] += red[(tid+s)*4+2];
      red[tid*4+3] += red[(tid+s)*4+3];
    }
    __syncthreads();
  }
  if (tid == 0) {
    atomicAdd(&g_acc[0], red[0]);
    atomicAdd(&g_acc[1], red[1]);
    atomicAdd(&g_acc[2], red[2]);
    atomicAdd(&g_acc[3], red[3]);
  }
}

__global__ void final_kernel(float* __restrict__ out) {
  if (threadIdx.x == 0 && blockIdx.x == 0) {
    double nfg = g_acc[0];
    double num = (nfg < 1.0) ? 1.0 : nfg;
    float li = (float)(g_acc[1] / num);
    float lo = (float)(g_acc[2] / num);
    float lc = (float)(g_acc[3] / num);
    out[0] = 5.0f * li + lo;   // REG_W * loss_iou + loss_obj
    out[1] = li;
    out[2] = lo;
    out[3] = lc;
  }
}

extern "C" void kernel_launch(void* const* d_in, const int* in_sizes, int n_in,
                              void* d_out, int out_size, void* d_ws, size_t ws_size,
                              hipStream_t stream) {
  const float* p0 = (const float*)d_in[0];
  const float* p1 = (const float*)d_in[1];
  const float* p2 = (const float*)d_in[2];
  const float* lb = (const float*)d_in[3];
  float* out = (float*)d_out;

  hipLaunchKernelGGL(decode_kernel, dim3((NA + 255) / 256, NB), dim3(256), 0, stream, p0, p1, p2, lb);
  hipLaunchKernelGGL(topk1_kernel,  dim3(NG, NB, NSPLIT), dim3(256), 0, stream, lb);
  hipLaunchKernelGGL(topk2_kernel,  dim3((NB*NG + 255) / 256), dim3(256), 0, stream, lb);
  hipLaunchKernelGGL(loss_kernel,   dim3((NA + 255) / 256, NB), dim3(256), 0, stream, p0, p1, p2, lb);
  hipLaunchKernelGGL(final_kernel,  dim3(1), dim3(64), 0, stream, out);
}

// Round 3
// 348.946 us; speedup vs baseline: 1.2779x; 1.0876x over previous
//
#include <hip/hip_runtime.h>
#include <math.h>

#define NCLS 10
#define NB   16
#define NG   60
#define NA   33600          // 160*160 + 80*80 + 40*40
#define BA   (NB*NA)        // 537600
#define NSEG 525            // NA/64
#define NW   8              // waves per (b,g) topk block

// ---- static device scratch ----
__device__ double g_acc[4];                 // nfg, sum_iou, sum_obj, sum_cls
__device__ int    g_nmatch[BA];
__device__ int    g_gsum[BA];
__device__ float4 g_box[BA];                // bx, by, bw, bh
__device__ float4 g_meta[BA];               // xc, yc, (fg ? rad : -rad), S
__device__ float  g_obj[BA];
__device__ float  g_D[(size_t)NCLS*BA];     // class-major: D[c*BA + b*NA + a]
__device__ unsigned long long g_fgmask[NB*NSEG];
// per-(b,g,wave) sorted top-10 lists
__device__ unsigned long long s_kv [(size_t)NB*NG*NW*10];
__device__ float              s_iou[(size_t)NB*NG*NW*10];

__device__ __forceinline__ void anchor_geom(int a, int& H, int& W, float& s, int& h, int& w, int& lvl) {
  if (a < 25600)      { lvl = 0; H = 160; W = 160; s = 8.f;  h = a / 160;            w = a - h*160; }
  else if (a < 32000) { lvl = 1; H = 80;  W = 80;  s = 16.f; int r = a - 25600; h = r / 80;  w = r - h*80; }
  else                { lvl = 2; H = 40;  W = 40;  s = 32.f; int r = a - 32000; h = r / 40;  w = r - h*40; }
}

// monotone float->uint key (order-preserving for all finite floats)
__device__ __forceinline__ unsigned int fkey(float f) {
  unsigned int b = __float_as_uint(f);
  return (b & 0x80000000u) ? ~b : (b | 0x80000000u);
}

// ---- Kernel A: init + decode + cls-cost precompute + fg flag + fg bitmask ----
__global__ __launch_bounds__(256) void decode_kernel(const float* __restrict__ p0,
                                                     const float* __restrict__ p1,
                                                     const float* __restrict__ p2,
                                                     const float* __restrict__ lb) {
  __shared__ float lab[NG*5];
  __shared__ int   lval[NG];
  int b = blockIdx.y, tid = threadIdx.x;
  if (b == 0 && blockIdx.x == 0 && tid < 4) g_acc[tid] = 0.0;
  for (int i = tid; i < NG*5; i += 256) lab[i] = lb[(size_t)b*NG*5 + i];
  __syncthreads();
  if (tid < NG) {
    float s = lab[tid*5] + lab[tid*5+1] + lab[tid*5+2] + lab[tid*5+3] + lab[tid*5+4];
    lval[tid] = (s > 0.f) ? 1 : 0;
  }
  __syncthreads();
  int a = blockIdx.x * 256 + tid;
  if (a >= NA) return;
  int idx = b * NA + a;
  g_nmatch[idx] = 0;
  g_gsum[idx]   = 0;

  int H, W, h, w, lvl; float st;
  anchor_geom(a, H, W, st, h, w, lvl);
  const float* pp = (lvl == 0) ? p0 : ((lvl == 1) ? p1 : p2);
  size_t cs = (size_t)H * W;
  size_t base = (size_t)b * 15 * cs + (size_t)h * W + w;

  float tx = pp[base], ty = pp[base+cs], tw = pp[base+2*cs], th = pp[base+3*cs], to = pp[base+4*cs];
  g_box[idx] = make_float4((tx + (float)w) * st, (ty + (float)h) * st,
                           expf(tw) * st, expf(th) * st);
  g_obj[idx] = to;

  float so = 1.f / (1.f + __expf(-to));
  float S = 0.f;
  for (int c = 0; c < NCLS; c++) {
    float xl = pp[base + (size_t)(5 + c) * cs];
    float sc = 1.f / (1.f + __expf(-xl));
    float p  = sqrtf(sc * so);
    float L  = __logf(p + 1e-12f);
    float M  = __logf(1.f - p + 1e-12f);
    S += M;
    g_D[(size_t)c*BA + idx] = L - M;
  }

  float xc = ((float)w + 0.5f) * st;
  float yc = ((float)h + 0.5f) * st;
  float rad = 2.5f * st;
  int fg = 0;
  for (int g = 0; g < NG; g++) {
    if (!lval[g]) continue;
    float gx = lab[g*5+1], gy = lab[g*5+2], gw = lab[g*5+3], gh = lab[g*5+4];
    float l  = xc - (gx - gw*0.5f);
    float r  = (gx + gw*0.5f) - xc;
    float t  = yc - (gy - gh*0.5f);
    float bo = (gy + gh*0.5f) - yc;
    float m1 = fminf(fminf(l, r), fminf(t, bo));
    float cl = xc - gx + rad, cr = gx + rad - xc, ct = yc - gy + rad, cb = gy + rad - yc;
    float m2 = fminf(fminf(cl, cr), fminf(ct, cb));
    if (m1 > 0.f || m2 > 0.f) { fg = 1; break; }
  }
  g_meta[idx] = make_float4(xc, yc, fg ? rad : -rad, S);

  unsigned long long m = __ballot(fg);
  if ((tid & 63) == 0) g_fgmask[b*NSEG + (a >> 6)] = m;
}

// ---- Kernel B1: per-(b,g) sparse scan of fg anchors, register top-10, wave butterfly ----
__global__ __launch_bounds__(512) void topk1_kernel(const float* __restrict__ lb) {
  int g = blockIdx.x, b = blockIdx.y;
  int tid = threadIdx.x, lane = tid & 63, wv = tid >> 6;
  const float* L = &lb[((size_t)b*NG + g)*5];
  float l0 = L[0], l1 = L[1], l2 = L[2], l3 = L[3], l4 = L[4];
  if (!(l0 + l1 + l2 + l3 + l4 > 0.f)) return;

  int   gc = (int)l0;
  float gx = l1, gy = l2, gw = l3, gh = l4;
  float a1x = gx - gw*0.5f, a1y = gy - gh*0.5f, a2x = gx + gw*0.5f, a2y = gy + gh*0.5f;
  float garea = gw * gh;
  const float* Dc = &g_D[(size_t)gc*BA];
  int bbase = b * NA;
  const unsigned long long* FM = &g_fgmask[b*NSEG];

  unsigned long long kv[10]; float iv[10];
  #pragma unroll
  for (int k = 0; k < 10; k++) { kv[k] = ~0ULL; iv[k] = 0.f; }

  auto ins_kv = [&](unsigned long long key) {
    if (key < kv[9]) {
      kv[9] = key;
      #pragma unroll
      for (int k = 9; k > 0; k--) {
        if (kv[k] < kv[k-1]) { unsigned long long t = kv[k]; kv[k] = kv[k-1]; kv[k-1] = t; }
      }
    }
  };
  auto ins_iou = [&](float w) {
    if (w > iv[9]) {
      iv[9] = w;
      #pragma unroll
      for (int k = 9; k > 0; k--) {
        if (iv[k] > iv[k-1]) { float t = iv[k]; iv[k] = iv[k-1]; iv[k-1] = t; }
      }
    }
  };

  for (int seg = wv; seg < NSEG; seg += NW) {
    unsigned long long m = FM[seg];
    if (m == 0ULL) continue;
    if ((m >> lane) & 1ULL) {
      int a = seg * 64 + lane;
      int idx = bbase + a;
      float4 B = g_box[idx];
      float4 M = g_meta[idx];
      float Dv = Dc[idx];
      float b1x = B.x - B.z*0.5f, b1y = B.y - B.w*0.5f;
      float b2x = B.x + B.z*0.5f, b2y = B.y + B.w*0.5f;
      float wx = fminf(a2x, b2x) - fmaxf(a1x, b1x); wx = wx > 0.f ? wx : 0.f;
      float wy = fminf(a2y, b2y) - fmaxf(a1y, b1y); wy = wy > 0.f ? wy : 0.f;
      float inter = wx * wy;
      float iou = inter / (garea + B.z*B.w - inter + 1e-8f);
      float xc = M.x, yc = M.y, rad = M.z;   // fg => M.z = +rad
      bool inb = fminf(fminf(xc - a1x, a2x - xc), fminf(yc - a1y, a2y - yc)) > 0.f;
      bool inc = fminf(fminf(xc - gx + rad, gx + rad - xc), fminf(yc - gy + rad, gy + rad - yc)) > 0.f;
      float cost = -(Dv + M.w) + 3.0f * (-logf(iou + 1e-8f));
      if (!(inb && inc)) cost += 100000.0f;
      ins_kv(((unsigned long long)fkey(cost) << 32) | (unsigned int)a);
      ins_iou(iou);
    }
  }

  // wave butterfly merge: complementary lanes hold disjoint anchor sets
  #pragma unroll
  for (int m = 1; m < 64; m <<= 1) {
    unsigned long long pk[10]; float pu[10];
    #pragma unroll
    for (int k = 0; k < 10; k++) {
      pk[k] = __shfl_xor(kv[k], m);
      pu[k] = __shfl_xor(iv[k], m);
    }
    #pragma unroll
    for (int k = 0; k < 10; k++) { ins_kv(pk[k]); ins_iou(pu[k]); }
  }

  if (lane == 0) {
    size_t slot = (((size_t)b*NG + g)*NW + wv) * 10;
    #pragma unroll
    for (int k = 0; k < 10; k++) { s_kv[slot+k] = kv[k]; s_iou[slot+k] = iv[k]; }
  }
}

// ---- Kernel B2: merge NW wave-lists per (b,g), dyn_k, scatter matches ----
__global__ __launch_bounds__(256) void topk2_kernel(const float* __restrict__ lb) {
  int t = blockIdx.x * 256 + threadIdx.x;
  if (t >= NB * NG) return;
  int b = t / NG, g = t - b * NG;
  const float* L = &lb[(size_t)t * 5];
  if (!(L[0] + L[1] + L[2] + L[3] + L[4] > 0.f)) return;

  size_t base = (size_t)t * (NW*10);
  unsigned long long kv[10]; float iv[10];
  #pragma unroll
  for (int k = 0; k < 10; k++) { kv[k] = s_kv[base+k]; iv[k] = s_iou[base+k]; }

  for (int l = 1; l < NW; l++) {
    size_t o = base + (size_t)l*10;
    #pragma unroll
    for (int k = 0; k < 10; k++) {
      unsigned long long key = s_kv[o+k];
      if (key < kv[9]) {
        kv[9] = key;
        #pragma unroll
        for (int k2 = 9; k2 > 0; k2--) {
          if (kv[k2] < kv[k2-1]) { unsigned long long tt = kv[k2]; kv[k2] = kv[k2-1]; kv[k2-1] = tt; }
        }
      }
      float w = s_iou[o+k];
      if (w > iv[9]) {
        iv[9] = w;
        #pragma unroll
        for (int k2 = 9; k2 > 0; k2--) {
          if (iv[k2] > iv[k2-1]) { float tv = iv[k2]; iv[k2] = iv[k2-1]; iv[k2-1] = tv; }
        }
      }
    }
  }

  float ss = 0.f;
  #pragma unroll
  for (int k = 0; k < 10; k++) ss += iv[k];   // descending order, same sum order as ref
  int dynk = (int)ss;
  if (dynk < 1)  dynk = 1;
  if (dynk > 10) dynk = 10;
  for (int k = 0; k < dynk; k++) {
    int a = (int)(unsigned int)(kv[k] & 0xFFFFFFFFu);
    atomicAdd(&g_nmatch[b*NA + a], 1);
    atomicAdd(&g_gsum[b*NA + a], g);
  }
}

// ---- Kernel C: dedup (argmin over g), per-anchor losses, fused block reduce ----
__global__ __launch_bounds__(256) void loss_kernel(const float* __restrict__ p0,
                                                   const float* __restrict__ p1,
                                                   const float* __restrict__ p2,
                                                   const float* __restrict__ lb) {
  __shared__ float  lab[NG*5];
  __shared__ int    lval[NG];
  __shared__ double red[256*4];
  int b = blockIdx.y, tid = threadIdx.x;
  for (int i = tid; i < NG*5; i += 256) lab[i] = lb[(size_t)b*NG*5 + i];
  __syncthreads();
  if (tid < NG) {
    float s = lab[tid*5] + lab[tid*5+1] + lab[tid*5+2] + lab[tid*5+3] + lab[tid*5+4];
    lval[tid] = (s > 0.f) ? 1 : 0;
  }
  __syncthreads();

  int a = blockIdx.x * 256 + tid;
  double t_nfg = 0.0, t_iou = 0.0, t_obj = 0.0, t_cls = 0.0;

  if (a < NA) {
    int idx = b * NA + a;
    float x  = g_obj[idx];
    int   nm = g_nmatch[idx];
    float t  = (nm > 0) ? 1.f : 0.f;
    float bce = fmaxf(x, 0.f) - x * t + log1pf(expf(-fabsf(x)));
    float pr  = 1.f / (1.f + expf(-x));
    float pt  = (nm > 0) ? pr : (1.f - pr);
    float wf  = (nm > 0) ? 0.25f : 0.75f;
    float om  = 1.f - pt;
    t_obj = (double)(bce * wf * om * om);

    if (nm > 0) {
      t_nfg = 1.0;
      float4 B = g_box[idx];
      float4 Mt = g_meta[idx];
      float px = B.x, py = B.y, pw = B.z, ph = B.w;
      float b1x = px - pw*0.5f, b1y = py - ph*0.5f, b2x = px + pw*0.5f, b2y = py + ph*0.5f;
      int mg;
      if (nm == 1) {
        mg = g_gsum[idx];
      } else {
        float xc = Mt.x, yc = Mt.y, rad = fabsf(Mt.z), S = Mt.w;
        int fg = (Mt.z > 0.f) ? 1 : 0;
        float best = INFINITY; int bg = 0;
        for (int g = 0; g < NG; g++) {
          float gx = lab[g*5+1], gy = lab[g*5+2], gw = lab[g*5+3], gh = lab[g*5+4];
          int gcl = (int)lab[g*5];
          int v = lval[g];
          float a1x = gx - gw*0.5f, a1y = gy - gh*0.5f, a2x = gx + gw*0.5f, a2y = gy + gh*0.5f;
          float wx = fminf(a2x, b2x) - fmaxf(a1x, b1x); wx = wx > 0.f ? wx : 0.f;
          float wy = fminf(a2y, b2y) - fmaxf(a1y, b1y); wy = wy > 0.f ? wy : 0.f;
          float inter = wx * wy;
          float iou = inter / (gw*gh + pw*ph - inter + 1e-8f);
          float l = xc - a1x, r = a2x - xc, tt = yc - a1y, bo = a2y - yc;
          bool inb = (fminf(fminf(l, r), fminf(tt, bo)) > 0.f) && v;
          float cl = xc - gx + rad, cr = gx + rad - xc, ct = yc - gy + rad, cb = gy + rad - yc;
          bool inc = (fminf(fminf(cl, cr), fminf(ct, cb)) > 0.f) && v;
          float clsc = -(g_D[(size_t)gcl*BA + idx] + S);
          float cost = clsc + 3.0f * (-logf(iou + 1e-8f));
          if (!(inb && inc)) cost += 100000.0f;
          if (!fg || !v)     cost += 1000000.0f;
          if (cost < best) { best = cost; bg = g; }   // strict < : first-index tie-break
        }
        mg = bg;
      }

      float gx = lab[mg*5+1], gy = lab[mg*5+2], gw = lab[mg*5+3], gh = lab[mg*5+4];
      int mcls = (int)lab[mg*5];
      float a1x = gx - gw*0.5f, a1y = gy - gh*0.5f, a2x = gx + gw*0.5f, a2y = gy + gh*0.5f;
      float wx = fminf(a2x, b2x) - fmaxf(a1x, b1x); wx = wx > 0.f ? wx : 0.f;
      float wy = fminf(a2y, b2y) - fmaxf(a1y, b1y); wy = wy > 0.f ? wy : 0.f;
      float inter = wx * wy;
      float miou = inter / (gw*gh + pw*ph - inter + 1e-8f);  // == forward-loss IoU bit-exact

      t_iou = (double)(1.f - miou * miou);

      int H, W, h, w, lvl; float st;
      anchor_geom(a, H, W, st, h, w, lvl);
      const float* pp = (lvl == 0) ? p0 : ((lvl == 1) ? p1 : p2);
      size_t cs = (size_t)H * W;
      size_t base = (size_t)b * 15 * cs + (size_t)h * W + w;
      float sc = 0.f;
      for (int c = 0; c < NCLS; c++) {
        float xl = pp[base + (size_t)(5 + c) * cs];
        float ctg = (c == mcls) ? miou : 0.f;
        sc += fmaxf(xl, 0.f) - xl * ctg + log1pf(expf(-fabsf(xl)));
      }
      t_cls = (double)sc;
    }
  }

  red[tid*4+0] = t_nfg; red[tid*4+1] = t_iou; red[tid*4+2] = t_obj; red[tid*4+3] = t_cls;
  __syncthreads();
  for (int s = 128; s > 0; s >>= 1) {
    if (tid < s) {
      red[tid*4+0] += red[(tid+s)*4+0];
      red[tid*4+1] += red[(tid+s)*4+1];
      red[tid*4+2] += red[(tid+s)*4+2];
      red[tid*4+3] += red[(tid+s)*4+3];
    }
    __syncthreads();
  }
  if (tid == 0) {
    atomicAdd(&g_acc[0], red[0]);
    atomicAdd(&g_acc[1], red[1]);
    atomicAdd(&g_acc[2], red[2]);
    atomicAdd(&g_acc[3], red[3]);
  }
}

__global__ void final_kernel(float* __restrict__ out) {
  if (threadIdx.x == 0 && blockIdx.x == 0) {
    double nfg = g_acc[0];
    double num = (nfg < 1.0) ? 1.0 : nfg;
    float li = (float)(g_acc[1] / num);
    float lo = (float)(g_acc[2] / num);
    float lc = (float)(g_acc[3] / num);
    out[0] = 5.0f * li + lo;   // REG_W * loss_iou + loss_obj
    out[1] = li;
    out[2] = lo;
    out[3] = lc;
  }
}

extern "C" void kernel_launch(void* const* d_in, const int* in_sizes, int n_in,
                              void* d_out, int out_size, void* d_ws, size_t ws_size,
                              hipStream_t stream) {
  const float* p0 = (const float*)d_in[0];
  const float* p1 = (const float*)d_in[1];
  const float* p2 = (const float*)d_in[2];
  const float* lb = (const float*)d_in[3];
  float* out = (float*)d_out;

  hipLaunchKernelGGL(decode_kernel, dim3((NA + 255) / 256, NB), dim3(256), 0, stream, p0, p1, p2, lb);
  hipLaunchKernelGGL(topk1_kernel,  dim3(NG, NB), dim3(512), 0, stream, lb);
  hipLaunchKernelGGL(topk2_kernel,  dim3((NB*NG + 255) / 256), dim3(256), 0, stream, lb);
  hipLaunchKernelGGL(loss_kernel,   dim3((NA + 255) / 256, NB), dim3(256), 0, stream, p0, p1, p2, lb);
  hipLaunchKernelGGL(final_kernel,  dim3(1), dim3(64), 0, stream, out);
}

// Round 4
// 302.834 us; speedup vs baseline: 1.4725x; 1.1523x over previous
//
#include <hip/hip_runtime.h>
#include <math.h>

#define NCLS 10
#define NB   16
#define NG   60
#define NA   33600          // 160*160 + 80*80 + 40*40
#define BA   (NB*NA)        // 537600
#define NW   4              // waves per topk1 block

// ---- static device scratch ----
__device__ double g_acc[4];                 // nfg, sum_iou, sum_obj, sum_cls
__device__ int    g_fcount[NB];             // fg count per image
__device__ int    g_nmatch[BA];
__device__ int    g_gsum[BA];
__device__ int    g_slot[BA];               // compact slot (fg anchors only)
__device__ float4 g_box[BA];                // bx, by, bw, bh  (all anchors; loss path)
__device__ float4 g_meta[BA];               // xc, yc, (fg?rad:-rad), S (all anchors; loss path)
// compacted per-image fg-anchor data
__device__ float4 g_cbox [BA];              // [b][j] box
__device__ float4 g_cmeta[BA];              // [b][j] xc, yc, S, idx_bits
__device__ float  g_cD   [(size_t)NB*NCLS*NA];  // [b][c][j] class-major
// per-(b,g,wave) sorted top-10 lists
__device__ unsigned long long s_kv [(size_t)NB*NG*NW*10];
__device__ float              s_iou[(size_t)NB*NG*NW*10];

__device__ __forceinline__ void anchor_geom(int a, int& H, int& W, float& s, int& h, int& w, int& lvl) {
  if (a < 25600)      { lvl = 0; H = 160; W = 160; s = 8.f;  h = a / 160;            w = a - h*160; }
  else if (a < 32000) { lvl = 1; H = 80;  W = 80;  s = 16.f; int r = a - 25600; h = r / 80;  w = r - h*80; }
  else                { lvl = 2; H = 40;  W = 40;  s = 32.f; int r = a - 32000; h = r / 40;  w = r - h*40; }
}

// monotone float->uint key (order-preserving for all finite floats)
__device__ __forceinline__ unsigned int fkey(float f) {
  unsigned int b = __float_as_uint(f);
  return (b & 0x80000000u) ? ~b : (b | 0x80000000u);
}

__global__ __launch_bounds__(64) void init_kernel() {
  int i = threadIdx.x;
  if (i < 4)  g_acc[i] = 0.0;
  if (i < NB) g_fcount[i] = 0;
}

// ---- Kernel A: decode + cls-cost precompute + fg flag + compaction ----
__global__ __launch_bounds__(256) void decode_kernel(const float* __restrict__ p0,
                                                     const float* __restrict__ p1,
                                                     const float* __restrict__ p2,
                                                     const float* __restrict__ lb) {
  __shared__ float lab[NG*5];
  __shared__ int   lval[NG];
  int b = blockIdx.y, tid = threadIdx.x;
  for (int i = tid; i < NG*5; i += 256) lab[i] = lb[(size_t)b*NG*5 + i];
  __syncthreads();
  if (tid < NG) {
    float s = lab[tid*5] + lab[tid*5+1] + lab[tid*5+2] + lab[tid*5+3] + lab[tid*5+4];
    lval[tid] = (s > 0.f) ? 1 : 0;
  }
  __syncthreads();

  int a = blockIdx.x * 256 + tid;
  bool valid = a < NA;
  int aa = valid ? a : 0;
  int idx = b * NA + aa;

  float4 boxv = make_float4(0.f,0.f,0.f,0.f);
  float xc = 0.f, yc = 0.f, S = 0.f;
  float Dl[NCLS];
  int fg = 0;

  if (valid) {
    g_nmatch[idx] = 0;
    g_gsum[idx]   = 0;

    int H, W, h, w, lvl; float st;
    anchor_geom(aa, H, W, st, h, w, lvl);
    const float* pp = (lvl == 0) ? p0 : ((lvl == 1) ? p1 : p2);
    size_t cs = (size_t)H * W;
    size_t base = (size_t)b * 15 * cs + (size_t)h * W + w;

    float tx = pp[base], ty = pp[base+cs], tw = pp[base+2*cs], th = pp[base+3*cs], to = pp[base+4*cs];
    boxv = make_float4((tx + (float)w) * st, (ty + (float)h) * st,
                       __expf(tw) * st, __expf(th) * st);
    g_box[idx] = boxv;

    float so = 1.f / (1.f + __expf(-to));
    #pragma unroll
    for (int c = 0; c < NCLS; c++) {
      float xl = pp[base + (size_t)(5 + c) * cs];
      float sc = 1.f / (1.f + __expf(-xl));
      float p  = sqrtf(sc * so);
      float L  = __logf(p + 1e-12f);
      float M  = __logf(1.f - p + 1e-12f);
      S += M;
      Dl[c] = L - M;
    }

    xc = ((float)w + 0.5f) * st;
    yc = ((float)h + 0.5f) * st;
    float rad = 2.5f * st;
    for (int g = 0; g < NG; g++) {
      if (!lval[g]) continue;
      float gx = lab[g*5+1], gy = lab[g*5+2], gw = lab[g*5+3], gh = lab[g*5+4];
      float l  = xc - (gx - gw*0.5f);
      float r  = (gx + gw*0.5f) - xc;
      float t  = yc - (gy - gh*0.5f);
      float bo = (gy + gh*0.5f) - yc;
      float m1 = fminf(fminf(l, r), fminf(t, bo));
      float cl = xc - gx + rad, cr = gx + rad - xc, ct = yc - gy + rad, cb = gy + rad - yc;
      float m2 = fminf(fminf(cl, cr), fminf(ct, cb));
      if (m1 > 0.f || m2 > 0.f) { fg = 1; break; }
    }
    g_meta[idx] = make_float4(xc, yc, fg ? rad : -rad, S);
  }

  // wave-aggregated compaction of fg anchors (order-free: keys carry idx)
  unsigned long long mask = __ballot(fg != 0);
  if (mask) {
    int lane = tid & 63;
    int leader = __ffsll((unsigned long long)mask) - 1;
    int cbase = 0;
    if (lane == leader) cbase = atomicAdd(&g_fcount[b], __popcll(mask));
    cbase = __shfl(cbase, leader, 64);
    if (fg) {
      int j = cbase + (int)__popcll(mask & ((1ULL << lane) - 1ULL));
      size_t cb = (size_t)b * NA + j;
      g_cbox[cb]  = boxv;
      g_cmeta[cb] = make_float4(xc, yc, S, __int_as_float(aa));
      #pragma unroll
      for (int c = 0; c < NCLS; c++) g_cD[((size_t)b*NCLS + c)*NA + j] = Dl[c];
      g_slot[idx] = j;
    }
  }
}

// ---- Kernel B1: per-(b,g) dense scan of compacted fg anchors ----
__global__ __launch_bounds__(256) void topk1_kernel(const float* __restrict__ lb) {
  int fid = blockIdx.x;                 // XCD-clustering remap: images {2r,2r+1} -> XCD r
  int t8 = fid >> 3;
  int b  = ((fid & 7) << 1) + (t8 >= 60 ? 1 : 0);
  int g  = t8 - (t8 >= 60 ? 60 : 0);
  int tid = threadIdx.x, lane = tid & 63, wv = tid >> 6;

  const float* L = &lb[((size_t)b*NG + g)*5];
  float l0 = L[0], l1 = L[1], l2 = L[2], l3 = L[3], l4 = L[4];
  if (!(l0 + l1 + l2 + l3 + l4 > 0.f)) return;

  int   gc = (int)l0;
  float gx = l1, gy = l2, gw = l3, gh = l4;
  float a1x = gx - gw*0.5f, a1y = gy - gh*0.5f, a2x = gx + gw*0.5f, a2y = gy + gh*0.5f;
  float garea = gw * gh;
  int F = g_fcount[b];
  const float4* CB = &g_cbox [(size_t)b*NA];
  const float4* CM = &g_cmeta[(size_t)b*NA];
  const float*  CD = &g_cD[((size_t)b*NCLS + gc)*NA];

  unsigned long long kv[10]; float iv[10];
  #pragma unroll
  for (int k = 0; k < 10; k++) { kv[k] = ~0ULL; iv[k] = 0.f; }

  for (int j = tid; j < F; j += 256) {
    float4 B = CB[j];
    float4 M = CM[j];
    float Dv = CD[j];
    int a = __float_as_int(M.w);
    float b1x = B.x - B.z*0.5f, b1y = B.y - B.w*0.5f;
    float b2x = B.x + B.z*0.5f, b2y = B.y + B.w*0.5f;
    float wx = fminf(a2x, b2x) - fmaxf(a1x, b1x); wx = wx > 0.f ? wx : 0.f;
    float wy = fminf(a2y, b2y) - fmaxf(a1y, b1y); wy = wy > 0.f ? wy : 0.f;
    float inter = wx * wy;
    float iou = inter / (garea + B.z*B.w - inter + 1e-8f);
    float xc = M.x, yc = M.y;
    float rad = (a < 25600) ? 20.f : ((a < 32000) ? 40.f : 80.f);
    bool inb = fminf(fminf(xc - a1x, a2x - xc), fminf(yc - a1y, a2y - yc)) > 0.f;
    bool inc = fminf(fminf(xc - gx + rad, gx + rad - xc), fminf(yc - gy + rad, gy + rad - yc)) > 0.f;
    float cost = -(Dv + M.z) + 3.0f * (-__logf(iou + 1e-8f));
    if (!(inb && inc)) cost += 100000.0f;

    unsigned long long key = ((unsigned long long)fkey(cost) << 32) | (unsigned int)a;
    if (key < kv[9]) {
      kv[9] = key;
      #pragma unroll
      for (int k = 9; k > 0; k--) {
        if (kv[k] < kv[k-1]) { unsigned long long t = kv[k]; kv[k] = kv[k-1]; kv[k-1] = t; }
      }
    }
    if (iou > iv[9]) {
      iv[9] = iou;
      #pragma unroll
      for (int k = 9; k > 0; k--) {
        if (iv[k] > iv[k-1]) { float t = iv[k]; iv[k] = iv[k-1]; iv[k-1] = t; }
      }
    }
  }

  // wave-level extraction merge -> sorted top-10 per wave
  size_t slot = (((size_t)b*NG + g)*NW + wv) * 10;
  for (int k = 0; k < 10; k++) {
    unsigned long long m = kv[0];
    #pragma unroll
    for (int d = 1; d < 64; d <<= 1) {
      unsigned long long o = __shfl_xor(m, d);
      if (o < m) m = o;
    }
    if (m == ~0ULL) {        // exhausted: pad
      if (lane == 0) for (int k2 = k; k2 < 10; k2++) s_kv[slot+k2] = ~0ULL;
      break;
    }
    if (lane == 0) s_kv[slot+k] = m;
    if (kv[0] == m) {        // unique key -> exactly one lane pops
      #pragma unroll
      for (int j2 = 0; j2 < 9; j2++) kv[j2] = kv[j2+1];
      kv[9] = ~0ULL;
    }
  }
  for (int k = 0; k < 10; k++) {
    float m = iv[0];
    #pragma unroll
    for (int d = 1; d < 64; d <<= 1) m = fmaxf(m, __shfl_xor(m, d));
    if (m <= 0.f) {          // rest are zeros
      if (lane == 0) for (int k2 = k; k2 < 10; k2++) s_iou[slot+k2] = 0.f;
      break;
    }
    if (lane == 0) s_iou[slot+k] = m;
    unsigned long long pm = __ballot(iv[0] == m);
    if (lane == __ffsll((unsigned long long)pm) - 1) {
      #pragma unroll
      for (int j2 = 0; j2 < 9; j2++) iv[j2] = iv[j2+1];
      iv[9] = 0.f;
    }
  }
}

// ---- Kernel B2: merge NW wave-lists per (b,g), dyn_k, scatter matches ----
__global__ __launch_bounds__(64) void topk2_kernel(const float* __restrict__ lb) {
  int t = blockIdx.x * 64 + threadIdx.x;
  if (t >= NB * NG) return;
  int b = t / NG, g = t - b * NG;
  const float* L = &lb[(size_t)t * 5];
  if (!(L[0] + L[1] + L[2] + L[3] + L[4] > 0.f)) return;

  size_t base = (size_t)t * (NW*10);
  unsigned long long kv[10]; float iv[10];
  #pragma unroll
  for (int k = 0; k < 10; k++) { kv[k] = s_kv[base+k]; iv[k] = s_iou[base+k]; }

  for (int l = 1; l < NW; l++) {
    size_t o = base + (size_t)l*10;
    #pragma unroll
    for (int k = 0; k < 10; k++) {
      unsigned long long key = s_kv[o+k];
      if (key < kv[9]) {
        kv[9] = key;
        #pragma unroll
        for (int k2 = 9; k2 > 0; k2--) {
          if (kv[k2] < kv[k2-1]) { unsigned long long tt = kv[k2]; kv[k2] = kv[k2-1]; kv[k2-1] = tt; }
        }
      } else break;          // source sorted ascending
    }
    #pragma unroll
    for (int k = 0; k < 10; k++) {
      float w = s_iou[o+k];
      if (w > iv[9]) {
        iv[9] = w;
        #pragma unroll
        for (int k2 = 9; k2 > 0; k2--) {
          if (iv[k2] > iv[k2-1]) { float tv = iv[k2]; iv[k2] = iv[k2-1]; iv[k2-1] = tv; }
        }
      } else break;          // source sorted descending
    }
  }

  float ss = 0.f;
  #pragma unroll
  for (int k = 0; k < 10; k++) ss += iv[k];   // descending order, same sum order as ref
  int dynk = (int)ss;
  if (dynk < 1)  dynk = 1;
  if (dynk > 10) dynk = 10;
  for (int k = 0; k < dynk; k++) {
    if (kv[k] == ~0ULL) break;                 // defensive (shouldn't happen)
    int a = (int)(unsigned int)(kv[k] & 0xFFFFFFFFu);
    atomicAdd(&g_nmatch[b*NA + a], 1);
    atomicAdd(&g_gsum[b*NA + a], g);
  }
}

// ---- Kernel C: dedup (argmin over g), per-anchor losses, fused block reduce ----
__global__ __launch_bounds__(256) void loss_kernel(const float* __restrict__ p0,
                                                   const float* __restrict__ p1,
                                                   const float* __restrict__ p2,
                                                   const float* __restrict__ lb) {
  __shared__ float  lab[NG*5];
  __shared__ int    lval[NG];
  __shared__ double red[256*4];
  int b = blockIdx.y, tid = threadIdx.x;
  for (int i = tid; i < NG*5; i += 256) lab[i] = lb[(size_t)b*NG*5 + i];
  __syncthreads();
  if (tid < NG) {
    float s = lab[tid*5] + lab[tid*5+1] + lab[tid*5+2] + lab[tid*5+3] + lab[tid*5+4];
    lval[tid] = (s > 0.f) ? 1 : 0;
  }
  __syncthreads();

  int a = blockIdx.x * 256 + tid;
  double t_nfg = 0.0, t_iou = 0.0, t_obj = 0.0, t_cls = 0.0;

  if (a < NA) {
    int idx = b * NA + a;
    int H, W, h, w, lvl; float st;
    anchor_geom(a, H, W, st, h, w, lvl);
    const float* pp = (lvl == 0) ? p0 : ((lvl == 1) ? p1 : p2);
    size_t cs = (size_t)H * W;
    size_t base = (size_t)b * 15 * cs + (size_t)h * W + w;

    float x  = pp[base + 4*cs];
    int   nm = g_nmatch[idx];
    float t  = (nm > 0) ? 1.f : 0.f;
    float bce = fmaxf(x, 0.f) - x * t + log1pf(expf(-fabsf(x)));
    float pr  = 1.f / (1.f + expf(-x));
    float pt  = (nm > 0) ? pr : (1.f - pr);
    float wf  = (nm > 0) ? 0.25f : 0.75f;
    float om  = 1.f - pt;
    t_obj = (double)(bce * wf * om * om);

    if (nm > 0) {
      t_nfg = 1.0;
      float4 B  = g_box[idx];
      float4 Mt = g_meta[idx];
      float pw = B.z, ph = B.w;
      float b1x = B.x - pw*0.5f, b1y = B.y - ph*0.5f, b2x = B.x + pw*0.5f, b2y = B.y + ph*0.5f;
      int mg;
      if (nm == 1) {
        mg = g_gsum[idx];
      } else {
        // matched => fg, so the 1e6 term reduces to validity only
        float xc = Mt.x, yc = Mt.y, rad = fabsf(Mt.z), S = Mt.w;
        int j = g_slot[idx];
        const float* CDb = &g_cD[(size_t)b*NCLS*NA];
        float best = INFINITY; int bg = 0;
        for (int g = 0; g < NG; g++) {
          float gx = lab[g*5+1], gy = lab[g*5+2], gw = lab[g*5+3], gh = lab[g*5+4];
          int gcl = (int)lab[g*5];
          int v = lval[g];
          float a1x = gx - gw*0.5f, a1y = gy - gh*0.5f, a2x = gx + gw*0.5f, a2y = gy + gh*0.5f;
          float wx = fminf(a2x, b2x) - fmaxf(a1x, b1x); wx = wx > 0.f ? wx : 0.f;
          float wy = fminf(a2y, b2y) - fmaxf(a1y, b1y); wy = wy > 0.f ? wy : 0.f;
          float inter = wx * wy;
          float iou = inter / (gw*gh + pw*ph - inter + 1e-8f);
          float l = xc - a1x, r = a2x - xc, tt = yc - a1y, bo = a2y - yc;
          bool inb = (fminf(fminf(l, r), fminf(tt, bo)) > 0.f) && v;
          float cl = xc - gx + rad, cr = gx + rad - xc, ct = yc - gy + rad, cb = gy + rad - yc;
          bool inc = (fminf(fminf(cl, cr), fminf(ct, cb)) > 0.f) && v;
          float clsc = -(CDb[(size_t)gcl*NA + j] + S);
          float cost = clsc + 3.0f * (-__logf(iou + 1e-8f));
          if (!(inb && inc)) cost += 100000.0f;
          if (!v)            cost += 1000000.0f;
          if (cost < best) { best = cost; bg = g; }   // strict < : first-index tie-break
        }
        mg = bg;
      }

      float gx = lab[mg*5+1], gy = lab[mg*5+2], gw = lab[mg*5+3], gh = lab[mg*5+4];
      int mcls = (int)lab[mg*5];
      float a1x = gx - gw*0.5f, a1y = gy - gh*0.5f, a2x = gx + gw*0.5f, a2y = gy + gh*0.5f;
      float wx = fminf(a2x, b2x) - fmaxf(a1x, b1x); wx = wx > 0.f ? wx : 0.f;
      float wy = fminf(a2y, b2y) - fmaxf(a1y, b1y); wy = wy > 0.f ? wy : 0.f;
      float inter = wx * wy;
      float miou = inter / (gw*gh + pw*ph - inter + 1e-8f);  // == forward-loss IoU bit-exact

      t_iou = (double)(1.f - miou * miou);

      float sc = 0.f;
      #pragma unroll
      for (int c = 0; c < NCLS; c++) {
        float xl = pp[base + (size_t)(5 + c) * cs];
        float ctg = (c == mcls) ? miou : 0.f;
        sc += fmaxf(xl, 0.f) - xl * ctg + log1pf(expf(-fabsf(xl)));
      }
      t_cls = (double)sc;
    }
  }

  red[tid*4+0] = t_nfg; red[tid*4+1] = t_iou; red[tid*4+2] = t_obj; red[tid*4+3] = t_cls;
  __syncthreads();
  for (int s = 128; s > 0; s >>= 1) {
    if (tid < s) {
      red[tid*4+0] += red[(tid+s)*4+0];
      red[tid*4+1] += red[(tid+s)*4+1];
      red[tid*4+2] += red[(tid+s)*4+2];
      red[tid*4+3] += red[(tid+s)*4+3];
    }
    __syncthreads();
  }
  if (tid == 0) {
    atomicAdd(&g_acc[0], red[0]);
    atomicAdd(&g_acc[1], red[1]);
    atomicAdd(&g_acc[2], red[2]);
    atomicAdd(&g_acc[3], red[3]);
  }
}

__global__ void final_kernel(float* __restrict__ out) {
  if (threadIdx.x == 0 && blockIdx.x == 0) {
    double nfg = g_acc[0];
    double num = (nfg < 1.0) ? 1.0 : nfg;
    float li = (float)(g_acc[1] / num);
    float lo = (float)(g_acc[2] / num);
    float lc = (float)(g_acc[3] / num);
    out[0] = 5.0f * li + lo;   // REG_W * loss_iou + loss_obj
    out[1] = li;
    out[2] = lo;
    out[3] = lc;
  }
}

extern "C" void kernel_launch(void* const* d_in, const int* in_sizes, int n_in,
                              void* d_out, int out_size, void* d_ws, size_t ws_size,
                              hipStream_t stream) {
  const float* p0 = (const float*)d_in[0];
  const float* p1 = (const float*)d_in[1];
  const float* p2 = (const float*)d_in[2];
  const float* lb = (const float*)d_in[3];
  float* out = (float*)d_out;

  hipLaunchKernelGGL(init_kernel,   dim3(1), dim3(64), 0, stream);
  hipLaunchKernelGGL(decode_kernel, dim3((NA + 255) / 256, NB), dim3(256), 0, stream, p0, p1, p2, lb);
  hipLaunchKernelGGL(topk1_kernel,  dim3(NB*NG), dim3(256), 0, stream, lb);
  hipLaunchKernelGGL(topk2_kernel,  dim3((NB*NG + 63) / 64), dim3(64), 0, stream, lb);
  hipLaunchKernelGGL(loss_kernel,   dim3((NA + 255) / 256, NB), dim3(256), 0, stream, p0, p1, p2, lb);
  hipLaunchKernelGGL(final_kernel,  dim3(1), dim3(64), 0, stream, out);
}

// Round 5
// 289.325 us; speedup vs baseline: 1.5413x; 1.0467x over previous
//
#include <hip/hip_runtime.h>
#include <math.h>

#define NCLS 10
#define NB   16
#define NG   60
#define NA   33600          // 160*160 + 80*80 + 40*40
#define BA   (NB*NA)        // 537600
#define NW   4              // waves per topk1 block
#define NBLK_X 132          // ceil(NA/256)
#define NBLK_LOSS (NBLK_X*NB)

// ---- static device scratch (load-time zero; self-restoring across calls) ----
__device__ double g_acc[4];                 // nfg, sum_iou, sum_obj, sum_cls
__device__ int    g_done;                   // loss-block completion counter
__device__ int    g_fcount[NB];             // fg count per image
__device__ int    g_nmatch[BA];
__device__ int    g_gsum[BA];
__device__ int    g_slot[BA];               // compact slot (valid for fg anchors only)
// compacted per-image fg-anchor data
__device__ float4 g_cbox [BA];              // [b][j] bx,by,bw,bh
__device__ float4 g_cmeta[BA];              // [b][j] xc, yc, S, anchor_id_bits
__device__ float  g_cD   [(size_t)NB*NCLS*NA];  // [b][c][j] class-major
// per-(b,g,wave) sorted top-10 lists
__device__ unsigned long long s_kv [(size_t)NB*NG*NW*10];
__device__ float              s_iou[(size_t)NB*NG*NW*10];

__device__ __forceinline__ void anchor_geom(int a, int& H, int& W, float& s, int& h, int& w, int& lvl) {
  if (a < 25600)      { lvl = 0; H = 160; W = 160; s = 8.f;  h = a / 160;            w = a - h*160; }
  else if (a < 32000) { lvl = 1; H = 80;  W = 80;  s = 16.f; int r = a - 25600; h = r / 80;  w = r - h*80; }
  else                { lvl = 2; H = 40;  W = 40;  s = 32.f; int r = a - 32000; h = r / 40;  w = r - h*40; }
}

// monotone float->uint key (order-preserving for all finite floats)
__device__ __forceinline__ unsigned int fkey(float f) {
  unsigned int b = __float_as_uint(f);
  return (b & 0x80000000u) ? ~b : (b | 0x80000000u);
}

// ---- Kernel A: decode + cls-cost precompute + fg flag + block-aggregated compaction ----
__global__ __launch_bounds__(256) void decode_kernel(const float* __restrict__ p0,
                                                     const float* __restrict__ p1,
                                                     const float* __restrict__ p2,
                                                     const float* __restrict__ lb) {
  __shared__ float lab[NG*5];
  __shared__ int   lval[NG];
  __shared__ int   wbase[4];
  __shared__ int   bbase_s;
  int b = blockIdx.y, tid = threadIdx.x;
  for (int i = tid; i < NG*5; i += 256) lab[i] = lb[(size_t)b*NG*5 + i];
  __syncthreads();
  if (tid < NG) {
    float s = lab[tid*5] + lab[tid*5+1] + lab[tid*5+2] + lab[tid*5+3] + lab[tid*5+4];
    lval[tid] = (s > 0.f) ? 1 : 0;
  }
  __syncthreads();

  int a = blockIdx.x * 256 + tid;
  bool valid = a < NA;
  int aa = valid ? a : 0;
  int idx = b * NA + aa;

  float4 boxv = make_float4(0.f,0.f,0.f,0.f);
  float xc = 0.f, yc = 0.f, S = 0.f;
  float Dl[NCLS];
  int fg = 0;

  if (valid) {
    g_nmatch[idx] = 0;
    g_gsum[idx]   = 0;

    int H, W, h, w, lvl; float st;
    anchor_geom(aa, H, W, st, h, w, lvl);
    const float* pp = (lvl == 0) ? p0 : ((lvl == 1) ? p1 : p2);
    size_t cs = (size_t)H * W;
    size_t base = (size_t)b * 15 * cs + (size_t)h * W + w;

    float tx = pp[base], ty = pp[base+cs], tw = pp[base+2*cs], th = pp[base+3*cs], to = pp[base+4*cs];
    boxv = make_float4((tx + (float)w) * st, (ty + (float)h) * st,
                       __expf(tw) * st, __expf(th) * st);

    float so = 1.f / (1.f + __expf(-to));
    #pragma unroll
    for (int c = 0; c < NCLS; c++) {
      float xl = pp[base + (size_t)(5 + c) * cs];
      float sc = 1.f / (1.f + __expf(-xl));
      float p  = sqrtf(sc * so);
      float L  = __logf(p + 1e-12f);
      float M  = __logf(1.f - p + 1e-12f);
      S += M;
      Dl[c] = L - M;
    }

    xc = ((float)w + 0.5f) * st;
    yc = ((float)h + 0.5f) * st;
    float rad = 2.5f * st;
    for (int g = 0; g < NG; g++) {
      if (!lval[g]) continue;
      float gx = lab[g*5+1], gy = lab[g*5+2], gw = lab[g*5+3], gh = lab[g*5+4];
      float l  = xc - (gx - gw*0.5f);
      float r  = (gx + gw*0.5f) - xc;
      float t  = yc - (gy - gh*0.5f);
      float bo = (gy + gh*0.5f) - yc;
      float m1 = fminf(fminf(l, r), fminf(t, bo));
      float cl = xc - gx + rad, cr = gx + rad - xc, ct = yc - gy + rad, cb = gy + rad - yc;
      float m2 = fminf(fminf(cl, cr), fminf(ct, cb));
      if (m1 > 0.f || m2 > 0.f) { fg = 1; break; }
    }
  }

  // block-aggregated compaction: one atomic per block
  unsigned long long m = __ballot(fg != 0);
  int lane = tid & 63, wv = tid >> 6;
  if (lane == 0) wbase[wv] = __popcll(m);
  __syncthreads();
  if (tid == 0) {
    int t = 0;
    #pragma unroll
    for (int k = 0; k < 4; k++) { int c = wbase[k]; wbase[k] = t; t += c; }
    bbase_s = t ? atomicAdd(&g_fcount[b], t) : 0;
  }
  __syncthreads();
  if (fg) {
    int j = bbase_s + wbase[wv] + (int)__popcll(m & ((1ULL << lane) - 1ULL));
    size_t cb = (size_t)b * NA + j;
    g_cbox[cb]  = boxv;
    g_cmeta[cb] = make_float4(xc, yc, S, __int_as_float(aa));
    #pragma unroll
    for (int c = 0; c < NCLS; c++) g_cD[((size_t)b*NCLS + c)*NA + j] = Dl[c];
    g_slot[idx] = j;
  }
}

// ---- Kernel B1: per-(b,g) dense scan of compacted fg anchors ----
__global__ __launch_bounds__(256) void topk1_kernel(const float* __restrict__ lb) {
  int fid = blockIdx.x;                 // XCD-clustering remap: images {2r,2r+1} -> XCD r
  int t8 = fid >> 3;
  int b  = ((fid & 7) << 1) + (t8 >= 60 ? 1 : 0);
  int g  = t8 - (t8 >= 60 ? 60 : 0);
  int tid = threadIdx.x, lane = tid & 63, wv = tid >> 6;

  const float* L = &lb[((size_t)b*NG + g)*5];
  float l0 = L[0], l1 = L[1], l2 = L[2], l3 = L[3], l4 = L[4];
  if (!(l0 + l1 + l2 + l3 + l4 > 0.f)) return;

  int   gc = (int)l0;
  float gx = l1, gy = l2, gw = l3, gh = l4;
  float a1x = gx - gw*0.5f, a1y = gy - gh*0.5f, a2x = gx + gw*0.5f, a2y = gy + gh*0.5f;
  float garea = gw * gh;
  int F = g_fcount[b];
  const float4* CB = &g_cbox [(size_t)b*NA];
  const float4* CM = &g_cmeta[(size_t)b*NA];
  const float*  CD = &g_cD[((size_t)b*NCLS + gc)*NA];

  unsigned long long kv[10]; float iv[10];
  #pragma unroll
  for (int k = 0; k < 10; k++) { kv[k] = ~0ULL; iv[k] = 0.f; }

  for (int j = tid; j < F; j += 256) {
    float4 B = CB[j];
    float4 M = CM[j];
    float Dv = CD[j];
    int a = __float_as_int(M.w);
    float b1x = B.x - B.z*0.5f, b1y = B.y - B.w*0.5f;
    float b2x = B.x + B.z*0.5f, b2y = B.y + B.w*0.5f;
    float wx = fminf(a2x, b2x) - fmaxf(a1x, b1x); wx = wx > 0.f ? wx : 0.f;
    float wy = fminf(a2y, b2y) - fmaxf(a1y, b1y); wy = wy > 0.f ? wy : 0.f;
    float inter = wx * wy;
    float iou = inter / (garea + B.z*B.w - inter + 1e-8f);
    float xc = M.x, yc = M.y;
    float rad = (a < 25600) ? 20.f : ((a < 32000) ? 40.f : 80.f);
    bool inb = fminf(fminf(xc - a1x, a2x - xc), fminf(yc - a1y, a2y - yc)) > 0.f;
    bool inc = fminf(fminf(xc - gx + rad, gx + rad - xc), fminf(yc - gy + rad, gy + rad - yc)) > 0.f;
    float cost = -(Dv + M.z) + 3.0f * (-__logf(iou + 1e-8f));
    if (!(inb && inc)) cost += 100000.0f;

    unsigned long long key = ((unsigned long long)fkey(cost) << 32) | (unsigned int)a;
    if (key < kv[9]) {
      kv[9] = key;
      #pragma unroll
      for (int k = 9; k > 0; k--) {
        if (kv[k] < kv[k-1]) { unsigned long long t = kv[k]; kv[k] = kv[k-1]; kv[k-1] = t; }
      }
    }
    if (iou > iv[9]) {
      iv[9] = iou;
      #pragma unroll
      for (int k = 9; k > 0; k--) {
        if (iv[k] > iv[k-1]) { float t = iv[k]; iv[k] = iv[k-1]; iv[k-1] = t; }
      }
    }
  }

  // wave-level extraction merge -> sorted top-10 per wave
  size_t slot = (((size_t)b*NG + g)*NW + wv) * 10;
  for (int k = 0; k < 10; k++) {
    unsigned long long m = kv[0];
    #pragma unroll
    for (int d = 1; d < 64; d <<= 1) {
      unsigned long long o = __shfl_xor(m, d);
      if (o < m) m = o;
    }
    if (m == ~0ULL) {        // exhausted: pad
      if (lane == 0) for (int k2 = k; k2 < 10; k2++) s_kv[slot+k2] = ~0ULL;
      break;
    }
    if (lane == 0) s_kv[slot+k] = m;
    if (kv[0] == m) {        // unique key -> exactly one lane pops
      #pragma unroll
      for (int j2 = 0; j2 < 9; j2++) kv[j2] = kv[j2+1];
      kv[9] = ~0ULL;
    }
  }
  for (int k = 0; k < 10; k++) {
    float m = iv[0];
    #pragma unroll
    for (int d = 1; d < 64; d <<= 1) m = fmaxf(m, __shfl_xor(m, d));
    if (m <= 0.f) {          // rest are zeros
      if (lane == 0) for (int k2 = k; k2 < 10; k2++) s_iou[slot+k2] = 0.f;
      break;
    }
    if (lane == 0) s_iou[slot+k] = m;
    unsigned long long pm = __ballot(iv[0] == m);
    if (lane == __ffsll((unsigned long long)pm) - 1) {
      #pragma unroll
      for (int j2 = 0; j2 < 9; j2++) iv[j2] = iv[j2+1];
      iv[9] = 0.f;
    }
  }
}

// ---- Kernel B2: merge NW wave-lists per (b,g), dyn_k, scatter matches ----
__global__ __launch_bounds__(64) void topk2_kernel(const float* __restrict__ lb) {
  int t = blockIdx.x * 64 + threadIdx.x;
  if (t >= NB * NG) return;
  int b = t / NG, g = t - b * NG;
  const float* L = &lb[(size_t)t * 5];
  if (!(L[0] + L[1] + L[2] + L[3] + L[4] > 0.f)) return;

  size_t base = (size_t)t * (NW*10);
  unsigned long long kv[10]; float iv[10];
  #pragma unroll
  for (int k = 0; k < 10; k++) { kv[k] = s_kv[base+k]; iv[k] = s_iou[base+k]; }

  for (int l = 1; l < NW; l++) {
    size_t o = base + (size_t)l*10;
    #pragma unroll
    for (int k = 0; k < 10; k++) {
      unsigned long long key = s_kv[o+k];
      if (key < kv[9]) {
        kv[9] = key;
        #pragma unroll
        for (int k2 = 9; k2 > 0; k2--) {
          if (kv[k2] < kv[k2-1]) { unsigned long long tt = kv[k2]; kv[k2] = kv[k2-1]; kv[k2-1] = tt; }
        }
      } else break;          // source sorted ascending
    }
    #pragma unroll
    for (int k = 0; k < 10; k++) {
      float w = s_iou[o+k];
      if (w > iv[9]) {
        iv[9] = w;
        #pragma unroll
        for (int k2 = 9; k2 > 0; k2--) {
          if (iv[k2] > iv[k2-1]) { float tv = iv[k2]; iv[k2] = iv[k2-1]; iv[k2-1] = tv; }
        }
      } else break;          // source sorted descending
    }
  }

  float ss = 0.f;
  #pragma unroll
  for (int k = 0; k < 10; k++) ss += iv[k];   // descending order, same sum order as ref
  int dynk = (int)ss;
  if (dynk < 1)  dynk = 1;
  if (dynk > 10) dynk = 10;
  for (int k = 0; k < dynk; k++) {
    if (kv[k] == ~0ULL) break;                 // defensive (shouldn't happen)
    int a = (int)(unsigned int)(kv[k] & 0xFFFFFFFFu);
    atomicAdd(&g_nmatch[b*NA + a], 1);
    atomicAdd(&g_gsum[b*NA + a], g);
  }
}

// ---- Kernel C: dedup (argmin over g), per-anchor losses, reduce + fused finalization ----
__global__ __launch_bounds__(256) void loss_kernel(const float* __restrict__ p0,
                                                   const float* __restrict__ p1,
                                                   const float* __restrict__ p2,
                                                   const float* __restrict__ lb,
                                                   float* __restrict__ out) {
  __shared__ float  lab[NG*5];
  __shared__ int    lval[NG];
  __shared__ double red[256*4];
  int b = blockIdx.y, tid = threadIdx.x;
  for (int i = tid; i < NG*5; i += 256) lab[i] = lb[(size_t)b*NG*5 + i];
  __syncthreads();
  if (tid < NG) {
    float s = lab[tid*5] + lab[tid*5+1] + lab[tid*5+2] + lab[tid*5+3] + lab[tid*5+4];
    lval[tid] = (s > 0.f) ? 1 : 0;
  }
  __syncthreads();

  int a = blockIdx.x * 256 + tid;
  double t_nfg = 0.0, t_iou = 0.0, t_obj = 0.0, t_cls = 0.0;

  if (a < NA) {
    int idx = b * NA + a;
    int H, W, h, w, lvl; float st;
    anchor_geom(a, H, W, st, h, w, lvl);
    const float* pp = (lvl == 0) ? p0 : ((lvl == 1) ? p1 : p2);
    size_t cs = (size_t)H * W;
    size_t base = (size_t)b * 15 * cs + (size_t)h * W + w;

    float x  = pp[base + 4*cs];
    int   nm = g_nmatch[idx];
    float t  = (nm > 0) ? 1.f : 0.f;
    float bce = fmaxf(x, 0.f) - x * t + log1pf(expf(-fabsf(x)));
    float pr  = 1.f / (1.f + expf(-x));
    float pt  = (nm > 0) ? pr : (1.f - pr);
    float wf  = (nm > 0) ? 0.25f : 0.75f;
    float om  = 1.f - pt;
    t_obj = (double)(bce * wf * om * om);

    if (nm > 0) {
      t_nfg = 1.0;
      int j = g_slot[idx];
      float4 B  = g_cbox [(size_t)b*NA + j];
      float4 Mt = g_cmeta[(size_t)b*NA + j];
      float pw = B.z, ph = B.w;
      float b1x = B.x - pw*0.5f, b1y = B.y - ph*0.5f, b2x = B.x + pw*0.5f, b2y = B.y + ph*0.5f;
      int mg;
      if (nm == 1) {
        mg = g_gsum[idx];
      } else {
        // matched => fg, so the 1e6 term reduces to validity only
        float xc = Mt.x, yc = Mt.y, S = Mt.z;
        float rad = 2.5f * st;
        const float* CDb = &g_cD[(size_t)b*NCLS*NA];
        float best = INFINITY; int bg = 0;
        for (int g = 0; g < NG; g++) {
          float gx = lab[g*5+1], gy = lab[g*5+2], gw = lab[g*5+3], gh = lab[g*5+4];
          int gcl = (int)lab[g*5];
          int v = lval[g];
          float a1x = gx - gw*0.5f, a1y = gy - gh*0.5f, a2x = gx + gw*0.5f, a2y = gy + gh*0.5f;
          float wx = fminf(a2x, b2x) - fmaxf(a1x, b1x); wx = wx > 0.f ? wx : 0.f;
          float wy = fminf(a2y, b2y) - fmaxf(a1y, b1y); wy = wy > 0.f ? wy : 0.f;
          float inter = wx * wy;
          float iou = inter / (gw*gh + pw*ph - inter + 1e-8f);
          float l = xc - a1x, r = a2x - xc, tt = yc - a1y, bo = a2y - yc;
          bool inb = (fminf(fminf(l, r), fminf(tt, bo)) > 0.f) && v;
          float cl = xc - gx + rad, cr = gx + rad - xc, ct = yc - gy + rad, cb = gy + rad - yc;
          bool inc = (fminf(fminf(cl, cr), fminf(ct, cb)) > 0.f) && v;
          float clsc = -(CDb[(size_t)gcl*NA + j] + S);
          float cost = clsc + 3.0f * (-__logf(iou + 1e-8f));
          if (!(inb && inc)) cost += 100000.0f;
          if (!v)            cost += 1000000.0f;
          if (cost < best) { best = cost; bg = g; }   // strict < : first-index tie-break
        }
        mg = bg;
      }

      float gx = lab[mg*5+1], gy = lab[mg*5+2], gw = lab[mg*5+3], gh = lab[mg*5+4];
      int mcls = (int)lab[mg*5];
      float a1x = gx - gw*0.5f, a1y = gy - gh*0.5f, a2x = gx + gw*0.5f, a2y = gy + gh*0.5f;
      float wx = fminf(a2x, b2x) - fmaxf(a1x, b1x); wx = wx > 0.f ? wx : 0.f;
      float wy = fminf(a2y, b2y) - fmaxf(a1y, b1y); wy = wy > 0.f ? wy : 0.f;
      float inter = wx * wy;
      float miou = inter / (gw*gh + pw*ph - inter + 1e-8f);  // == forward-loss IoU bit-exact

      t_iou = (double)(1.f - miou * miou);

      float sc = 0.f;
      #pragma unroll
      for (int c = 0; c < NCLS; c++) {
        float xl = pp[base + (size_t)(5 + c) * cs];
        float ctg = (c == mcls) ? miou : 0.f;
        sc += fmaxf(xl, 0.f) - xl * ctg + log1pf(expf(-fabsf(xl)));
      }
      t_cls = (double)sc;
    }
  }

  red[tid*4+0] = t_nfg; red[tid*4+1] = t_iou; red[tid*4+2] = t_obj; red[tid*4+3] = t_cls;
  __syncthreads();
  for (int s = 128; s > 0; s >>= 1) {
    if (tid < s) {
      red[tid*4+0] += red[(tid+s)*4+0];
      red[tid*4+1] += red[(tid+s)*4+1];
      red[tid*4+2] += red[(tid+s)*4+2];
      red[tid*4+3] += red[(tid+s)*4+3];
    }
    __syncthreads();
  }
  if (tid == 0) {
    atomicAdd(&g_acc[0], red[0]);
    atomicAdd(&g_acc[1], red[1]);
    atomicAdd(&g_acc[2], red[2]);
    atomicAdd(&g_acc[3], red[3]);
    __threadfence();
    int old = atomicAdd(&g_done, 1);
    if (old == NBLK_LOSS - 1) {
      // last block: finalize outputs and reset scratch counters for the next call
      __threadfence();
      double nfg = atomicAdd(&g_acc[0], 0.0);
      double si  = atomicAdd(&g_acc[1], 0.0);
      double so  = atomicAdd(&g_acc[2], 0.0);
      double sc  = atomicAdd(&g_acc[3], 0.0);
      double num = (nfg < 1.0) ? 1.0 : nfg;
      float li = (float)(si / num);
      float lo = (float)(so / num);
      float lc = (float)(sc / num);
      out[0] = 5.0f * li + lo;   // REG_W * loss_iou + loss_obj
      out[1] = li;
      out[2] = lo;
      out[3] = lc;
      #pragma unroll
      for (int k = 0; k < 4; k++)
        atomicExch((unsigned long long*)&g_acc[k], 0ULL);
      for (int k = 0; k < NB; k++) atomicExch(&g_fcount[k], 0);
      atomicExch(&g_done, 0);
    }
  }
}

extern "C" void kernel_launch(void* const* d_in, const int* in_sizes, int n_in,
                              void* d_out, int out_size, void* d_ws, size_t ws_size,
                              hipStream_t stream) {
  const float* p0 = (const float*)d_in[0];
  const float* p1 = (const float*)d_in[1];
  const float* p2 = (const float*)d_in[2];
  const float* lb = (const float*)d_in[3];
  float* out = (float*)d_out;

  hipLaunchKernelGGL(decode_kernel, dim3(NBLK_X, NB), dim3(256), 0, stream, p0, p1, p2, lb);
  hipLaunchKernelGGL(topk1_kernel,  dim3(NB*NG), dim3(256), 0, stream, lb);
  hipLaunchKernelGGL(topk2_kernel,  dim3((NB*NG + 63) / 64), dim3(64), 0, stream, lb);
  hipLaunchKernelGGL(loss_kernel,   dim3(NBLK_X, NB), dim3(256), 0, stream, p0, p1, p2, lb, out);
}

// Round 6
// 211.950 us; speedup vs baseline: 2.1040x; 1.3651x over previous
//
#include <hip/hip_runtime.h>
#include <math.h>

#define NCLS 10
#define NB   16
#define NG   60
#define NA   33600          // 160*160 + 80*80 + 40*40
#define BA   (NB*NA)        // 537600
#define NW   4              // waves per topk1 block
#define NBLK_X 132          // ceil(NA/256)
#define NBLK_LOSS (NBLK_X*NB)

// ---- static device scratch (load-time zero; self-restoring across calls) ----
__device__ double g_part[NBLK_LOSS][4];     // per-loss-block partials (nfg, iou, obj, cls)
__device__ int    g_fcount[NB];             // fg count per image (reset by final_kernel)
__device__ int    g_nmatch[BA];             // all-zero between calls (self-cleaned by loss)
__device__ int    g_gsum[BA];               // all-zero between calls (self-cleaned by loss)
__device__ int    g_slot[BA];               // compact slot (valid for fg anchors only)
// compacted per-image fg-anchor data
__device__ float4 g_cbox [BA];              // [b][j] bx,by,bw,bh
__device__ float4 g_cmeta[BA];              // [b][j] xc, yc, S, anchor_id_bits
__device__ float  g_cD   [(size_t)NB*NCLS*NA];  // [b][c][j] class-major

__device__ __forceinline__ void anchor_geom(int a, int& H, int& W, float& s, int& h, int& w, int& lvl) {
  if (a < 25600)      { lvl = 0; H = 160; W = 160; s = 8.f;  h = a / 160;            w = a - h*160; }
  else if (a < 32000) { lvl = 1; H = 80;  W = 80;  s = 16.f; int r = a - 25600; h = r / 80;  w = r - h*80; }
  else                { lvl = 2; H = 40;  W = 40;  s = 32.f; int r = a - 32000; h = r / 40;  w = r - h*40; }
}

// monotone float->uint key (order-preserving for all finite floats)
__device__ __forceinline__ unsigned int fkey(float f) {
  unsigned int b = __float_as_uint(f);
  return (b & 0x80000000u) ? ~b : (b | 0x80000000u);
}

// ---- Kernel A: fg test (no loads) -> compact -> decode planes for fg lanes only ----
__global__ __launch_bounds__(256) void decode_kernel(const float* __restrict__ p0,
                                                     const float* __restrict__ p1,
                                                     const float* __restrict__ p2,
                                                     const float* __restrict__ lb) {
  __shared__ float lab[NG*5];
  __shared__ int   lval[NG];
  __shared__ int   wbase[4];
  __shared__ int   bbase_s;
  int b = blockIdx.y, tid = threadIdx.x;
  for (int i = tid; i < NG*5; i += 256) lab[i] = lb[(size_t)b*NG*5 + i];
  __syncthreads();
  if (tid < NG) {
    float s = lab[tid*5] + lab[tid*5+1] + lab[tid*5+2] + lab[tid*5+3] + lab[tid*5+4];
    lval[tid] = (s > 0.f) ? 1 : 0;
  }
  __syncthreads();

  int a = blockIdx.x * 256 + tid;
  bool valid = a < NA;
  int aa = valid ? a : 0;

  int H, W, h, w, lvl; float st;
  anchor_geom(aa, H, W, st, h, w, lvl);
  float xc = ((float)w + 0.5f) * st;
  float yc = ((float)h + 0.5f) * st;
  float rad = 2.5f * st;

  int fg = 0;
  if (valid) {
    for (int g = 0; g < NG; g++) {
      if (!lval[g]) continue;
      float gx = lab[g*5+1], gy = lab[g*5+2], gw = lab[g*5+3], gh = lab[g*5+4];
      float l  = xc - (gx - gw*0.5f);
      float r  = (gx + gw*0.5f) - xc;
      float t  = yc - (gy - gh*0.5f);
      float bo = (gy + gh*0.5f) - yc;
      float m1 = fminf(fminf(l, r), fminf(t, bo));
      float cl = xc - gx + rad, cr = gx + rad - xc, ct = yc - gy + rad, cb = gy + rad - yc;
      float m2 = fminf(fminf(cl, cr), fminf(ct, cb));
      if (m1 > 0.f || m2 > 0.f) { fg = 1; break; }
    }
  }

  // block-aggregated compaction: one atomic per block
  unsigned long long m = __ballot(fg != 0);
  int lane = tid & 63, wv = tid >> 6;
  if (lane == 0) wbase[wv] = __popcll(m);
  __syncthreads();
  if (tid == 0) {
    int t = 0;
    #pragma unroll
    for (int k = 0; k < 4; k++) { int c = wbase[k]; wbase[k] = t; t += c; }
    bbase_s = t ? atomicAdd(&g_fcount[b], t) : 0;
  }
  __syncthreads();

  if (fg) {
    // plane loads + transcendentals only for fg anchors
    const float* pp = (lvl == 0) ? p0 : ((lvl == 1) ? p1 : p2);
    size_t cs = (size_t)H * W;
    size_t base = (size_t)b * 15 * cs + (size_t)h * W + w;

    float tx = pp[base], ty = pp[base+cs], tw = pp[base+2*cs], th = pp[base+3*cs], to = pp[base+4*cs];
    float4 boxv = make_float4((tx + (float)w) * st, (ty + (float)h) * st,
                              __expf(tw) * st, __expf(th) * st);

    float so = 1.f / (1.f + __expf(-to));
    float S = 0.f;
    float Dl[NCLS];
    #pragma unroll
    for (int c = 0; c < NCLS; c++) {
      float xl = pp[base + (size_t)(5 + c) * cs];
      float sc = 1.f / (1.f + __expf(-xl));
      float p  = sqrtf(sc * so);
      float L  = __logf(p + 1e-12f);
      float M  = __logf(1.f - p + 1e-12f);
      S += M;
      Dl[c] = L - M;
    }

    int j = bbase_s + wbase[wv] + (int)__popcll(m & ((1ULL << lane) - 1ULL));
    size_t cb = (size_t)b * NA + j;
    g_cbox[cb]  = boxv;
    g_cmeta[cb] = make_float4(xc, yc, S, __int_as_float(aa));
    #pragma unroll
    for (int c = 0; c < NCLS; c++) g_cD[((size_t)b*NCLS + c)*NA + j] = Dl[c];
    g_slot[b * NA + aa] = j;
  }
}

// ---- Kernel B: per-(b,g) dense scan of compacted fg anchors + in-block merge + scatter ----
__global__ __launch_bounds__(256) void topk1_kernel(const float* __restrict__ lb) {
  __shared__ unsigned long long skv [NW*10];
  __shared__ float              siou[NW*10];
  int fid = blockIdx.x;                 // XCD-clustering remap: images {2r,2r+1} -> XCD r
  int t8 = fid >> 3;
  int b  = ((fid & 7) << 1) + (t8 >= 60 ? 1 : 0);
  int g  = t8 - (t8 >= 60 ? 60 : 0);
  int tid = threadIdx.x, lane = tid & 63, wv = tid >> 6;

  const float* L = &lb[((size_t)b*NG + g)*5];
  float l0 = L[0], l1 = L[1], l2 = L[2], l3 = L[3], l4 = L[4];
  if (!(l0 + l1 + l2 + l3 + l4 > 0.f)) return;

  int   gc = (int)l0;
  float gx = l1, gy = l2, gw = l3, gh = l4;
  float a1x = gx - gw*0.5f, a1y = gy - gh*0.5f, a2x = gx + gw*0.5f, a2y = gy + gh*0.5f;
  float garea = gw * gh;
  int F = g_fcount[b];
  const float4* CB = &g_cbox [(size_t)b*NA];
  const float4* CM = &g_cmeta[(size_t)b*NA];
  const float*  CD = &g_cD[((size_t)b*NCLS + gc)*NA];

  unsigned long long kv[10]; float iv[10];
  #pragma unroll
  for (int k = 0; k < 10; k++) { kv[k] = ~0ULL; iv[k] = 0.f; }

  for (int j = tid; j < F; j += 256) {
    float4 B = CB[j];
    float4 M = CM[j];
    float Dv = CD[j];
    int a = __float_as_int(M.w);
    float b1x = B.x - B.z*0.5f, b1y = B.y - B.w*0.5f;
    float b2x = B.x + B.z*0.5f, b2y = B.y + B.w*0.5f;
    float wx = fminf(a2x, b2x) - fmaxf(a1x, b1x); wx = wx > 0.f ? wx : 0.f;
    float wy = fminf(a2y, b2y) - fmaxf(a1y, b1y); wy = wy > 0.f ? wy : 0.f;
    float inter = wx * wy;
    float iou = inter / (garea + B.z*B.w - inter + 1e-8f);
    float xc = M.x, yc = M.y;
    float rad = (a < 25600) ? 20.f : ((a < 32000) ? 40.f : 80.f);
    bool inb = fminf(fminf(xc - a1x, a2x - xc), fminf(yc - a1y, a2y - yc)) > 0.f;
    bool inc = fminf(fminf(xc - gx + rad, gx + rad - xc), fminf(yc - gy + rad, gy + rad - yc)) > 0.f;
    float cost = -(Dv + M.z) + 3.0f * (-__logf(iou + 1e-8f));
    if (!(inb && inc)) cost += 100000.0f;

    unsigned long long key = ((unsigned long long)fkey(cost) << 32) | (unsigned int)a;
    if (key < kv[9]) {
      kv[9] = key;
      #pragma unroll
      for (int k = 9; k > 0; k--) {
        if (kv[k] < kv[k-1]) { unsigned long long t = kv[k]; kv[k] = kv[k-1]; kv[k-1] = t; }
      }
    }
    if (iou > iv[9]) {
      iv[9] = iou;
      #pragma unroll
      for (int k = 9; k > 0; k--) {
        if (iv[k] > iv[k-1]) { float t = iv[k]; iv[k] = iv[k-1]; iv[k-1] = t; }
      }
    }
  }

  // wave-level extraction merge -> sorted top-10 per wave (into LDS)
  for (int k = 0; k < 10; k++) {
    unsigned long long m = kv[0];
    #pragma unroll
    for (int d = 1; d < 64; d <<= 1) {
      unsigned long long o = __shfl_xor(m, d);
      if (o < m) m = o;
    }
    if (m == ~0ULL) {        // exhausted: pad
      if (lane == 0) for (int k2 = k; k2 < 10; k2++) skv[wv*10+k2] = ~0ULL;
      break;
    }
    if (lane == 0) skv[wv*10+k] = m;
    if (kv[0] == m) {        // unique key -> exactly one lane pops
      #pragma unroll
      for (int j2 = 0; j2 < 9; j2++) kv[j2] = kv[j2+1];
      kv[9] = ~0ULL;
    }
  }
  for (int k = 0; k < 10; k++) {
    float m = iv[0];
    #pragma unroll
    for (int d = 1; d < 64; d <<= 1) m = fmaxf(m, __shfl_xor(m, d));
    if (m <= 0.f) {          // rest are zeros
      if (lane == 0) for (int k2 = k; k2 < 10; k2++) siou[wv*10+k2] = 0.f;
      break;
    }
    if (lane == 0) siou[wv*10+k] = m;
    unsigned long long pm = __ballot(iv[0] == m);
    if (lane == __ffsll((unsigned long long)pm) - 1) {
      #pragma unroll
      for (int j2 = 0; j2 < 9; j2++) iv[j2] = iv[j2+1];
      iv[9] = 0.f;
    }
  }
  __syncthreads();

  // tid 0: 4-way merge of sorted lists, dyn_k, scatter matches
  if (tid == 0) {
    int pk[NW] = {0,0,0,0}, pi[NW] = {0,0,0,0};
    unsigned long long sel[10];
    #pragma unroll 1
    for (int k = 0; k < 10; k++) {
      unsigned long long best = ~0ULL; int bl = 0;
      #pragma unroll
      for (int l = 0; l < NW; l++) {
        unsigned long long v = skv[l*10 + pk[l]];
        if (v < best) { best = v; bl = l; }
      }
      sel[k] = best;
      if (pk[bl] < 9) pk[bl]++;
      else skv[bl*10+9] = ~0ULL;   // list exhausted
    }
    float ss = 0.f;
    #pragma unroll 1
    for (int k = 0; k < 10; k++) {
      float best = 0.f; int bl = 0;
      #pragma unroll
      for (int l = 0; l < NW; l++) {
        float v = siou[l*10 + pi[l]];
        if (v > best) { best = v; bl = l; }
      }
      ss += best;
      if (pi[bl] < 9) pi[bl]++;
      else siou[bl*10+9] = 0.f;    // list exhausted
    }
    int dynk = (int)ss;
    if (dynk < 1)  dynk = 1;
    if (dynk > 10) dynk = 10;
    for (int k = 0; k < dynk; k++) {
      if (sel[k] == ~0ULL) break;  // defensive
      int a = (int)(unsigned int)(sel[k] & 0xFFFFFFFFu);
      atomicAdd(&g_nmatch[b*NA + a], 1);
      atomicAdd(&g_gsum[b*NA + a], g);
    }
  }
}

// ---- Kernel C: dedup (argmin over g), per-anchor losses, per-block partial store ----
__global__ __launch_bounds__(256) void loss_kernel(const float* __restrict__ p0,
                                                   const float* __restrict__ p1,
                                                   const float* __restrict__ p2,
                                                   const float* __restrict__ lb) {
  __shared__ float  lab[NG*5];
  __shared__ int    lval[NG];
  __shared__ double red[256*4];
  int b = blockIdx.y, tid = threadIdx.x;
  for (int i = tid; i < NG*5; i += 256) lab[i] = lb[(size_t)b*NG*5 + i];
  __syncthreads();
  if (tid < NG) {
    float s = lab[tid*5] + lab[tid*5+1] + lab[tid*5+2] + lab[tid*5+3] + lab[tid*5+4];
    lval[tid] = (s > 0.f) ? 1 : 0;
  }
  __syncthreads();

  int a = blockIdx.x * 256 + tid;
  double t_nfg = 0.0, t_iou = 0.0, t_obj = 0.0, t_cls = 0.0;

  if (a < NA) {
    int idx = b * NA + a;
    int H, W, h, w, lvl; float st;
    anchor_geom(a, H, W, st, h, w, lvl);
    const float* pp = (lvl == 0) ? p0 : ((lvl == 1) ? p1 : p2);
    size_t cs = (size_t)H * W;
    size_t base = (size_t)b * 15 * cs + (size_t)h * W + w;

    float x  = pp[base + 4*cs];
    int   nm = g_nmatch[idx];
    float t  = (nm > 0) ? 1.f : 0.f;
    float bce = fmaxf(x, 0.f) - x * t + log1pf(expf(-fabsf(x)));
    float pr  = 1.f / (1.f + expf(-x));
    float pt  = (nm > 0) ? pr : (1.f - pr);
    float wf  = (nm > 0) ? 0.25f : 0.75f;
    float om  = 1.f - pt;
    t_obj = (double)(bce * wf * om * om);

    if (nm > 0) {
      t_nfg = 1.0;
      int mgsum = g_gsum[idx];
      g_nmatch[idx] = 0;           // self-clean for next call
      g_gsum[idx]   = 0;
      int j = g_slot[idx];
      float4 B  = g_cbox [(size_t)b*NA + j];
      float4 Mt = g_cmeta[(size_t)b*NA + j];
      float pw = B.z, ph = B.w;
      float b1x = B.x - pw*0.5f, b1y = B.y - ph*0.5f, b2x = B.x + pw*0.5f, b2y = B.y + ph*0.5f;
      int mg;
      if (nm == 1) {
        mg = mgsum;
      } else {
        // matched => fg, so the 1e6 term reduces to validity only
        float xc = Mt.x, yc = Mt.y, S = Mt.z;
        float rad = 2.5f * st;
        const float* CDb = &g_cD[(size_t)b*NCLS*NA];
        float best = INFINITY; int bg = 0;
        for (int g = 0; g < NG; g++) {
          float gx = lab[g*5+1], gy = lab[g*5+2], gw = lab[g*5+3], gh = lab[g*5+4];
          int gcl = (int)lab[g*5];
          int v = lval[g];
          float a1x = gx - gw*0.5f, a1y = gy - gh*0.5f, a2x = gx + gw*0.5f, a2y = gy + gh*0.5f;
          float wx = fminf(a2x, b2x) - fmaxf(a1x, b1x); wx = wx > 0.f ? wx : 0.f;
          float wy = fminf(a2y, b2y) - fmaxf(a1y, b1y); wy = wy > 0.f ? wy : 0.f;
          float inter = wx * wy;
          float iou = inter / (gw*gh + pw*ph - inter + 1e-8f);
          float l = xc - a1x, r = a2x - xc, tt = yc - a1y, bo = a2y - yc;
          bool inb = (fminf(fminf(l, r), fminf(tt, bo)) > 0.f) && v;
          float cl = xc - gx + rad, cr = gx + rad - xc, ct = yc - gy + rad, cb = gy + rad - yc;
          bool inc = (fminf(fminf(cl, cr), fminf(ct, cb)) > 0.f) && v;
          float clsc = -(CDb[(size_t)gcl*NA + j] + S);
          float cost = clsc + 3.0f * (-__logf(iou + 1e-8f));
          if (!(inb && inc)) cost += 100000.0f;
          if (!v)            cost += 1000000.0f;
          if (cost < best) { best = cost; bg = g; }   // strict < : first-index tie-break
        }
        mg = bg;
      }

      float gx = lab[mg*5+1], gy = lab[mg*5+2], gw = lab[mg*5+3], gh = lab[mg*5+4];
      int mcls = (int)lab[mg*5];
      float a1x = gx - gw*0.5f, a1y = gy - gh*0.5f, a2x = gx + gw*0.5f, a2y = gy + gh*0.5f;
      float wx = fminf(a2x, b2x) - fmaxf(a1x, b1x); wx = wx > 0.f ? wx : 0.f;
      float wy = fminf(a2y, b2y) - fmaxf(a1y, b1y); wy = wy > 0.f ? wy : 0.f;
      float inter = wx * wy;
      float miou = inter / (gw*gh + pw*ph - inter + 1e-8f);  // == forward-loss IoU bit-exact

      t_iou = (double)(1.f - miou * miou);

      float sc = 0.f;
      #pragma unroll
      for (int c = 0; c < NCLS; c++) {
        float xl = pp[base + (size_t)(5 + c) * cs];
        float ctg = (c == mcls) ? miou : 0.f;
        sc += fmaxf(xl, 0.f) - xl * ctg + log1pf(expf(-fabsf(xl)));
      }
      t_cls = (double)sc;
    }
  }

  red[tid] = t_nfg; red[256+tid] = t_iou; red[512+tid] = t_obj; red[768+tid] = t_cls;
  __syncthreads();
  for (int s = 128; s > 0; s >>= 1) {
    if (tid < s) {
      red[tid]     += red[tid+s];
      red[256+tid] += red[256+tid+s];
      red[512+tid] += red[512+tid+s];
      red[768+tid] += red[768+tid+s];
    }
    __syncthreads();
  }
  if (tid == 0) {
    int blk = b * NBLK_X + blockIdx.x;
    g_part[blk][0] = red[0];
    g_part[blk][1] = red[256];
    g_part[blk][2] = red[512];
    g_part[blk][3] = red[768];
  }
}

// ---- Kernel D: reduce per-block partials, finalize, reset fcount ----
__global__ __launch_bounds__(256) void final_kernel(float* __restrict__ out) {
  __shared__ double red[256];
  int tid = threadIdx.x;
  int cat = tid & 3;
  double s = 0.0;
  for (int blk = tid >> 2; blk < NBLK_LOSS; blk += 64) s += g_part[blk][cat];
  red[tid] = s;
  __syncthreads();
  for (int st = 128; st >= 4; st >>= 1) {
    if (tid < st) red[tid] += red[tid + st];
    __syncthreads();
  }
  if (tid == 0) {
    double nfg = red[0];
    double num = (nfg < 1.0) ? 1.0 : nfg;
    float li = (float)(red[1] / num);
    float lo = (float)(red[2] / num);
    float lc = (float)(red[3] / num);
    out[0] = 5.0f * li + lo;   // REG_W * loss_iou + loss_obj
    out[1] = li;
    out[2] = lo;
    out[3] = lc;
  }
  if (tid < NB) g_fcount[tid] = 0;   // self-restore for next call
}

extern "C" void kernel_launch(void* const* d_in, const int* in_sizes, int n_in,
                              void* d_out, int out_size, void* d_ws, size_t ws_size,
                              hipStream_t stream) {
  const float* p0 = (const float*)d_in[0];
  const float* p1 = (const float*)d_in[1];
  const float* p2 = (const float*)d_in[2];
  const float* lb = (const float*)d_in[3];
  float* out = (float*)d_out;

  hipLaunchKernelGGL(decode_kernel, dim3(NBLK_X, NB), dim3(256), 0, stream, p0, p1, p2, lb);
  hipLaunchKernelGGL(topk1_kernel,  dim3(NB*NG), dim3(256), 0, stream, lb);
  hipLaunchKernelGGL(loss_kernel,   dim3(NBLK_X, NB), dim3(256), 0, stream, p0, p1, p2, lb);
  hipLaunchKernelGGL(final_kernel,  dim3(1), dim3(256), 0, stream, out);
}